// Round 1
// baseline (1283.719 us; speedup 1.0000x reference)
//
#include <hip/hip_runtime.h>
#include <stdint.h>

#define DD 128

typedef __bf16 bf16x8 __attribute__((ext_vector_type(8)));
typedef float f32x4 __attribute__((ext_vector_type(4)));
typedef unsigned short u16;
typedef u16 u16x8 __attribute__((ext_vector_type(8)));

// Plain cast -> single HW cvt instruction (RNE), vs ~5 VALU ops manual.
__device__ __forceinline__ u16 f2bf(float f) {
  union { __bf16 h; u16 u; } v; v.h = (__bf16)f; return v.u;
}
__device__ __forceinline__ float bf2f(u16 b) {
  union { uint32_t u; float f; } v; v.u = (uint32_t)b << 16; return v.f;
}
__device__ __forceinline__ float silu_f(float x) {
  return x / (1.0f + __expf(-x));
}
__device__ __forceinline__ uint32_t pkbf(float lo, float hi) {
  return (uint32_t)f2bf(lo) | ((uint32_t)f2bf(hi) << 16);
}

// ---- f32 A staging (streamed): issue to regs / bf16-convert into LDS ----
// LDS layout: Ab[row*128 + ((cc ^ (row&7))<<3) + (k&7)]  (cc = k>>3).
struct ARegs { float4 v[8][2]; };

__device__ __forceinline__ void issue_A(ARegs& r, const float* __restrict__ src,
                                        int base, int M, int tid) {
#pragma unroll
  for (int i = 0; i < 8; ++i) {
    int id = tid + (i << 8);
    int row = id >> 4;
    int cc = id & 15;
    if (base + row < M) {
      const float4* p = (const float4*)(src + (size_t)(base + row) * DD + cc * 8);
      r.v[i][0] = p[0]; r.v[i][1] = p[1];
    } else {
      r.v[i][0] = make_float4(0.f, 0.f, 0.f, 0.f);
      r.v[i][1] = make_float4(0.f, 0.f, 0.f, 0.f);
    }
  }
}

__device__ __forceinline__ void write_A(u16* Ab, const ARegs& r, int tid) {
#pragma unroll
  for (int i = 0; i < 8; ++i) {
    int id = tid + (i << 8);
    int row = id >> 4;
    int cc = id & 15;
    u16x8 o;
    o[0] = f2bf(r.v[i][0].x); o[1] = f2bf(r.v[i][0].y);
    o[2] = f2bf(r.v[i][0].z); o[3] = f2bf(r.v[i][0].w);
    o[4] = f2bf(r.v[i][1].x); o[5] = f2bf(r.v[i][1].y);
    o[6] = f2bf(r.v[i][1].z); o[7] = f2bf(r.v[i][1].w);
    *(u16x8*)&Ab[row * DD + ((cc ^ (row & 7)) << 3)] = o;
  }
}

// ---- MFMA stage. B fragments direct from global (L2-resident wt[n][k] bf16).
// Same lane->k bijection on A and B so any hw k-permutation cancels.
__device__ __forceinline__ void mma_stage(const u16* Ab, const u16* __restrict__ wt,
                                          f32x4 acc[4][4], int lane, int wr, int wc) {
  int g = lane >> 4, r15 = lane & 15, s = r15 & 7;
  const u16* wbase = wt + (size_t)(wc * 64 + r15) * DD;
#pragma unroll
  for (int kk = 0; kk < 4; ++kk) {
    int ko = ((kk << 2) | g) << 3;
    bf16x8 bfr[4];
#pragma unroll
    for (int n = 0; n < 4; ++n)
      bfr[n] = *(const bf16x8*)&wbase[n * 16 * DD + ko];
    bf16x8 af[4];
#pragma unroll
    for (int m = 0; m < 4; ++m) {
      int rr = wr * 64 + m * 16 + r15;
      af[m] = *(const bf16x8*)&Ab[rr * DD + ((((kk << 2) | g) ^ s) << 3)];
    }
#pragma unroll
    for (int m = 0; m < 4; ++m)
#pragma unroll
      for (int n = 0; n < 4; ++n)
        acc[m][n] = __builtin_amdgcn_mfma_f32_16x16x32_bf16(af[m], bfr[n], acc[m][n], 0, 0, 0);
  }
}

// acc init with per-column bias folded in (C-in of first MFMA). col = wc*64+n*16+l15,
// identical for all 4 j-rows of a reg -> one splat per n. bias==null -> zeros.
__device__ __forceinline__ void init_acc(f32x4 a[4][4], const float* __restrict__ bias,
                                         int lane, int wc) {
  int l15 = lane & 15;
#pragma unroll
  for (int n = 0; n < 4; ++n) {
    float b = bias ? bias[wc * 64 + n * 16 + l15] : 0.f;
    f32x4 v = {b, b, b, b};
#pragma unroll
    for (int m = 0; m < 4; ++m) a[m][n] = v;
  }
}

// C/D: col=lane&15, row=(lane>>4)*4+reg. shfl-pair -> u32 per 2 cols; store
// to out[row*rs + co + col]. (bias now pre-folded into acc init.)
__device__ __forceinline__ void store_acc(const f32x4 acc[4][4], u16* __restrict__ out,
                                          size_t rs, int co, int base, int M,
                                          int lane, int wr, int wc) {
  int l15 = lane & 15;
  bool oddl = lane & 1;
#pragma unroll
  for (int m = 0; m < 4; ++m) {
    int rb = wr * 64 + m * 16 + ((lane >> 4) << 2);
#pragma unroll
    for (int j = 0; j < 4; ++j) {
      int row = rb + j;
      bool act = (base + row < M);
      size_t rowoff = (size_t)(base + row) * rs + co;
#pragma unroll
      for (int n0 = 0; n0 < 4; n0 += 2) {
        int c0 = wc * 64 + n0 * 16 + l15;
        float v0 = acc[m][n0][j];
        float v1 = acc[m][n0 + 1][j];
        float t0 = __shfl_xor(v0, 1);
        float t1 = __shfl_xor(v1, 1);
        uint32_t pk = oddl ? pkbf(t1, v1) : pkbf(v0, t0);
        int col2 = oddl ? (c0 + 15) : c0;
        if (act) *(uint32_t*)&out[rowoff + col2] = pk;
      }
    }
  }
}

// ================= projection GEMMs (pure streaming, no gathers/atomics) ====
// Grid-stride multi-tile blocks with LDS double-buffer: issue next tile's 16
// HBM loads BEFORE the current tile's 4-stage compute, bf16-convert+LDS-write
// them after it. One barrier per tile; staging latency hides under MFMA+stores.
// (Previous one-tile-per-block version: full serial fill/drain per 128 rows ->
// MfmaUtil 7.8%, HBM 23%, stall-dominated.)
// bounds (256,2): ARegs(64) now lives across the compute; cap 256 avoids spill.
template <bool FOUR>
__global__ void __launch_bounds__(256, 2) proj_kernel(
    int M, int ntiles, const float* __restrict__ src, const u16* __restrict__ wt,
    const float* __restrict__ bF,  // folded biases [3][128]: sg+dg+eg, du, su
    u16* __restrict__ o_sg, u16* __restrict__ o_dgdu, u16* __restrict__ o_su) {
  __shared__ u16 Ab[2][128 * DD];  // 2 x 32 KB, fits 64 KB static LDS exactly
  int tid = threadIdx.x, lane = tid & 63, wid = tid >> 6;
  int wr = wid >> 1, wc = wid & 1;
  int G = (int)gridDim.x;
  int t = blockIdx.x;
  ARegs ar;
  issue_A(ar, src, t * 128, M, tid);
  write_A(Ab[0], ar, tid);
  int cur = 0;
  f32x4 acc[4][4];
  for (;;) {
    int tn = t + G;
    bool more = (tn < ntiles);
    if (more) issue_A(ar, src, tn * 128, M, tid);  // in flight during compute
    __syncthreads();  // prev write_A (into Ab[cur]) visible to all waves
    const u16* A = Ab[cur];
    int base = t * 128;
    init_acc(acc, FOUR ? bF : nullptr, lane, wc);
    mma_stage(A, wt + 0 * 16384, acc, lane, wr, wc);        // sg (or egp)
    store_acc(acc, o_sg, DD, 0, base, M, lane, wr, wc);
    if (FOUR) {
      init_acc(acc, nullptr, lane, wc);
      mma_stage(A, wt + 1 * 16384, acc, lane, wr, wc);      // dg (bias in sg)
      store_acc(acc, o_dgdu, 2 * DD, 0, base, M, lane, wr, wc);
      init_acc(acc, bF + 128, lane, wc);
      mma_stage(A, wt + 3 * 16384, acc, lane, wr, wc);      // du + bdu
      store_acc(acc, o_dgdu, 2 * DD, DD, base, M, lane, wr, wc);
      init_acc(acc, bF + 256, lane, wc);
      mma_stage(A, wt + 4 * 16384, acc, lane, wr, wc);      // su + bsu
      store_acc(acc, o_su, DD, 0, base, M, lane, wr, wc);
    }
    if (!more) break;
    write_A(Ab[cur ^ 1], ar, tid);  // loads landed during compute; other buffer
    cur ^= 1;
    t = tn;
  }
}

// ================= CSR build =================
__global__ void __launch_bounds__(256) hist_kernel(const int* __restrict__ dst,
                                                   int Me, int* __restrict__ cnt) {
  int i = blockIdx.x * blockDim.x + threadIdx.x;
  if (i < Me) atomicAdd(&cnt[dst[i]], 1);
}

__global__ void __launch_bounds__(256) scan1_kernel(const int* __restrict__ cnt, int M,
                                                    int* __restrict__ out,
                                                    int* __restrict__ bsum) {
  __shared__ int sh[256];
  int t = threadIdx.x;
  int i0 = blockIdx.x * 1024 + t * 4;
  int v[4];
#pragma unroll
  for (int k = 0; k < 4; ++k) v[k] = (i0 + k < M) ? cnt[i0 + k] : 0;
  int s = v[0] + v[1] + v[2] + v[3];
  sh[t] = s;
  __syncthreads();
#pragma unroll
  for (int off = 1; off < 256; off <<= 1) {
    int x = (t >= off) ? sh[t - off] : 0;
    __syncthreads();
    sh[t] += x;
    __syncthreads();
  }
  int run = sh[t] - s;  // exclusive
  if (t == 255) bsum[blockIdx.x] = sh[255];
#pragma unroll
  for (int k = 0; k < 4; ++k) {
    if (i0 + k < M) out[i0 + k] = run;
    run += v[k];
  }
}

__global__ void __launch_bounds__(256) scan2_kernel(int* __restrict__ bsum, int NB) {
  __shared__ int sh[512];
  int t = threadIdx.x;
  for (int i = t; i < 512; i += 256) sh[i] = (i < NB) ? bsum[i] : 0;
  __syncthreads();
  for (int off = 1; off < 512; off <<= 1) {
    int tmp[2];
#pragma unroll
    for (int q = 0; q < 2; ++q) {
      int i = t + q * 256;
      tmp[q] = (i >= off) ? sh[i - off] : 0;
    }
    __syncthreads();
#pragma unroll
    for (int q = 0; q < 2; ++q) sh[t + q * 256] += tmp[q];
    __syncthreads();
  }
  for (int i = t; i < NB; i += 256) bsum[i] = (i == 0) ? 0 : sh[i - 1];
}

__global__ void __launch_bounds__(256) scan3_kernel(int* __restrict__ rowptr,
                                                    const int* __restrict__ bscan,
                                                    int M, int Medges,
                                                    int* __restrict__ head) {
  int i = blockIdx.x * blockDim.x + threadIdx.x;
  if (i < M) {
    int v = rowptr[i] + bscan[i >> 10];
    rowptr[i] = v;
    head[i] = v;
  }
  if (i == 0) rowptr[M] = Medges;
}

// Counting-sort: slot s gets edge id + its src (4B scatters on L2-resident arrays).
__global__ void __launch_bounds__(256) eid_kernel(const int* __restrict__ src,
                                                  const int* __restrict__ dst, int Me,
                                                  int* __restrict__ head,
                                                  int* __restrict__ eids,
                                                  int* __restrict__ srcs) {
  int i = blockIdx.x * blockDim.x + threadIdx.x;
  if (i < Me) {
    int s = atomicAdd(&head[dst[i]], 1);
    eids[s] = i;
    srcs[s] = src[i];
  }
}

// ================= misc prep =================
// W (k-major [128][128] f32) -> wt[n*128+k] bf16.
__global__ void prep_weights(const float* __restrict__ w0, const float* __restrict__ w1,
                             const float* __restrict__ w2, const float* __restrict__ w3,
                             const float* __restrict__ w4, const float* __restrict__ w5,
                             const float* __restrict__ w6, const float* __restrict__ w7,
                             const float* __restrict__ w8, const float* __restrict__ w9,
                             u16* __restrict__ wt) {
  const float* W;
  switch (blockIdx.x) {
    case 0: W = w0; break; case 1: W = w1; break; case 2: W = w2; break;
    case 3: W = w3; break; case 4: W = w4; break; case 5: W = w5; break;
    case 6: W = w6; break; case 7: W = w7; break; case 8: W = w8; break;
    default: W = w9; break;
  }
  u16* dst = wt + blockIdx.x * 16384;
  for (int o = threadIdx.x; o < 16384; o += 256) {
    int n = o >> 7, k = o & 127;
    dst[o] = f2bf(W[k * DD + n]);
  }
}

// Folded bias table: [0..2]*128 = eu {sg+dg+eg, du, su}; [3..5]*128 = nu same.
__global__ void fold_bias(const float* __restrict__ e_sg, const float* __restrict__ e_dg,
                          const float* __restrict__ e_eg, const float* __restrict__ e_du,
                          const float* __restrict__ e_su,
                          const float* __restrict__ n_sg, const float* __restrict__ n_dg,
                          const float* __restrict__ n_eg, const float* __restrict__ n_du,
                          const float* __restrict__ n_su, float* __restrict__ out) {
  int i = threadIdx.x;
  if (i < 128) {
    out[i]        = e_sg[i] + e_dg[i] + e_eg[i];
    out[128 + i]  = e_du[i];
    out[256 + i]  = e_su[i];
    out[384 + i]  = n_sg[i] + n_dg[i] + n_eg[i];
    out[512 + i]  = n_du[i];
    out[640 + i]  = n_su[i];
  }
}

// ============ gather-finalize: 16 lanes/row, 8 cols/lane, 4 rows/wave ========
// per row r: for s in [rptr[r],rptr[r+1]):
//   e=eids[s], sv=srcs[s]
//   gate = silu(sg'[r] + dg[sv] + egp[e]); ax += gate * du'[sv]
// vx = su'[r] + ax; LN; silu; + resid(f32); write f32 out.
// (biases pre-folded: sg' = sg+bsg+bdg+beg, du' = du+bdu, su' = su+bsu)
__global__ void __launch_bounds__(256) gfin_kernel(
    int M, const int* __restrict__ rptr, const int* __restrict__ eids,
    const int* __restrict__ srcs,
    const u16* __restrict__ sg_t, const u16* __restrict__ dgdu_t,
    const u16* __restrict__ su_t, const u16* __restrict__ egp,
    const float* __restrict__ gamma, const float* __restrict__ beta,
    const float* __restrict__ resid, float* __restrict__ out) {
  int gtid = blockIdx.x * blockDim.x + threadIdx.x;
  int r = gtid >> 4;
  int l16 = gtid & 15;
  if (r >= M) return;
  int c = l16 * 8;

  u16x8 sgp = *(const u16x8*)&sg_t[(size_t)r * DD + c];
  float sg[8], ax[8];
#pragma unroll
  for (int k = 0; k < 8; ++k) { sg[k] = bf2f(sgp[k]); ax[k] = 0.f; }

  int segb = rptr[r], sege = rptr[r + 1];
  for (int s = segb; s < sege; ++s) {
    int e = eids[s];
    int sv = srcs[s];
    u16x8 gp = *(const u16x8*)&egp[(size_t)e * DD + c];
    u16x8 dgp = *(const u16x8*)&dgdu_t[(size_t)sv * (2 * DD) + c];
    u16x8 dup = *(const u16x8*)&dgdu_t[(size_t)sv * (2 * DD) + DD + c];
#pragma unroll
    for (int k = 0; k < 8; ++k) {
      float g = silu_f(sg[k] + bf2f(dgp[k]) + bf2f(gp[k]));
      ax[k] += g * bf2f(dup[k]);
    }
  }

  u16x8 sup = *(const u16x8*)&su_t[(size_t)r * DD + c];
  float v[8];
  float sum = 0.f;
#pragma unroll
  for (int k = 0; k < 8; ++k) { v[k] = bf2f(sup[k]) + ax[k]; sum += v[k]; }
#pragma unroll
  for (int off = 1; off <= 8; off <<= 1) sum += __shfl_xor(sum, off);
  float mean = sum * (1.0f / 128.0f);
  float sq = 0.f;
#pragma unroll
  for (int k = 0; k < 8; ++k) { v[k] -= mean; sq += v[k] * v[k]; }
#pragma unroll
  for (int off = 1; off <= 8; off <<= 1) sq += __shfl_xor(sq, off);
  float rs = rsqrtf(sq * (1.0f / 128.0f) + 1e-5f);

  float4 gm0 = *(const float4*)&gamma[c];
  float4 gm1 = *(const float4*)&gamma[c + 4];
  float4 bt0 = *(const float4*)&beta[c];
  float4 bt1 = *(const float4*)&beta[c + 4];
  float4 rr0 = *(const float4*)&resid[(size_t)r * DD + c];
  float4 rr1 = *(const float4*)&resid[(size_t)r * DD + c + 4];
  float gmv[8] = {gm0.x, gm0.y, gm0.z, gm0.w, gm1.x, gm1.y, gm1.z, gm1.w};
  float btv[8] = {bt0.x, bt0.y, bt0.z, bt0.w, bt1.x, bt1.y, bt1.z, bt1.w};
  float rrv[8] = {rr0.x, rr0.y, rr0.z, rr0.w, rr1.x, rr1.y, rr1.z, rr1.w};
  float o[8];
#pragma unroll
  for (int k = 0; k < 8; ++k)
    o[k] = silu_f(v[k] * rs * gmv[k] + btv[k]) + rrv[k];
  float4 o0 = {o[0], o[1], o[2], o[3]};
  float4 o1 = {o[4], o[5], o[6], o[7]};
  *(float4*)&out[(size_t)r * DD + c] = o0;
  *(float4*)&out[(size_t)r * DD + c + 4] = o1;
}

extern "C" void kernel_launch(void* const* d_in, const int* in_sizes, int n_in,
                              void* d_out, int out_size, void* d_ws, size_t ws_size,
                              hipStream_t stream) {
  const float* x   = (const float*)d_in[0];
  const float* ex  = (const float*)d_in[1];
  const float* lga = (const float*)d_in[2];
  const int* gei   = (const int*)d_in[3];
  const int* lgei  = (const int*)d_in[4];
  int N   = in_sizes[0] / DD;
  int E   = in_sizes[3] / 2;
  int ELG = in_sizes[4] / 2;

  char* p = (char*)d_ws;
  size_t off = 0;
  auto alloc = [&](size_t bytes) { char* q = p + off; off += (bytes + 255) & ~255ull; return q; };

  u16* wt     = (u16*)alloc((size_t)10 * 16384 * 2);
  float* biasF = (float*)alloc(768 * 4);
  u16* sgE    = (u16*)alloc((size_t)E * DD * 2);        // 128 MB
  u16* dgduE  = (u16*)alloc((size_t)E * 2 * DD * 2);    // 256 MB
  u16* suE    = (u16*)alloc((size_t)E * DD * 2);        // 128 MB
  int  maxME  = (ELG > E) ? ELG : E;
  u16* egpB   = (u16*)alloc((size_t)maxME * DD * 2);    // 128 MB, shared L1/L2
  u16* sgN    = (u16*)alloc((size_t)N * DD * 2);
  u16* dgduN  = (u16*)alloc((size_t)N * 2 * DD * 2);
  u16* suN    = (u16*)alloc((size_t)N * DD * 2);
  int* cnt_e  = (int*)alloc((size_t)E * 4);
  int* rptr_e = (int*)alloc((size_t)(E + 1) * 4);
  int* head_e = (int*)alloc((size_t)E * 4);
  int* eids_e = (int*)alloc((size_t)ELG * 4);
  int* srcs_e = (int*)alloc((size_t)ELG * 4);
  int* cnt_n  = (int*)alloc((size_t)N * 4);
  int* rptr_n = (int*)alloc((size_t)(N + 1) * 4);
  int* head_n = (int*)alloc((size_t)N * 4);
  int* eids_n = (int*)alloc((size_t)E * 4);
  int* srcs_n = (int*)alloc((size_t)E * 4);
  int* bsum   = (int*)alloc(512 * 4);
  if (ws_size < off) return;  // visible failure if ws too small

  float* xn_out = (float*)d_out;
  float* ea_out = (float*)d_out + (size_t)N * DD;

  // --- prep: weights + folded biases ---
  // wt slots 0..9 = eu{sg,dg,eg,du,su}, nu{sg,dg,eg,du,su}
  prep_weights<<<10, 256, 0, stream>>>(
      (const float*)d_in[5], (const float*)d_in[7], (const float*)d_in[9],
      (const float*)d_in[13], (const float*)d_in[11],
      (const float*)d_in[17], (const float*)d_in[19], (const float*)d_in[21],
      (const float*)d_in[25], (const float*)d_in[23], wt);
  fold_bias<<<1, 128, 0, stream>>>(
      (const float*)d_in[6], (const float*)d_in[8], (const float*)d_in[10],
      (const float*)d_in[14], (const float*)d_in[12],
      (const float*)d_in[18], (const float*)d_in[20], (const float*)d_in[22],
      (const float*)d_in[26], (const float*)d_in[24], biasF);

  // --- CSR builds: counts -> rowptr -> (eid, src) counting-sort ---
  hipMemsetAsync(cnt_e, 0, (size_t)E * 4, stream);
  hipMemsetAsync(cnt_n, 0, (size_t)N * 4, stream);
  hist_kernel<<<(ELG + 255) / 256, 256, 0, stream>>>(lgei + ELG, ELG, cnt_e);
  hist_kernel<<<(E + 255) / 256, 256, 0, stream>>>(gei + E, E, cnt_n);

  int NBe = (E + 1023) / 1024;
  scan1_kernel<<<NBe, 256, 0, stream>>>(cnt_e, E, rptr_e, bsum);
  scan2_kernel<<<1, 256, 0, stream>>>(bsum, NBe);
  scan3_kernel<<<(E + 255) / 256, 256, 0, stream>>>(rptr_e, bsum, E, ELG, head_e);
  eid_kernel<<<(ELG + 255) / 256, 256, 0, stream>>>(lgei, lgei + ELG, ELG, head_e,
                                                    eids_e, srcs_e);

  int NBn = (N + 1023) / 1024;
  scan1_kernel<<<NBn, 256, 0, stream>>>(cnt_n, N, rptr_n, bsum);
  scan2_kernel<<<1, 256, 0, stream>>>(bsum, NBn);
  scan3_kernel<<<(N + 255) / 256, 256, 0, stream>>>(rptr_n, bsum, N, E, head_n);
  eid_kernel<<<(E + 255) / 256, 256, 0, stream>>>(gei, gei + E, E, head_n,
                                                  eids_n, srcs_n);

  const int PG = 512;  // 2 blocks/CU, grid-stride over row tiles
  int ntE = (E + 127) / 128;   int gE = ntE < PG ? ntE : PG;
  int ntLG = (ELG + 127) / 128; int gLG = ntLG < PG ? ntLG : PG;
  int ntN = (N + 127) / 128;   int gN = ntN < PG ? ntN : PG;

  // --- Layer 1 (line graph; rows = g's edges) ---
  proj_kernel<true><<<gE, 256, 0, stream>>>(
      E, ntE, ex, wt, biasF, sgE, dgduE, suE);
  proj_kernel<false><<<gLG, 256, 0, stream>>>(
      ELG, ntLG, lga, wt + 2 * 16384, nullptr, egpB, nullptr, nullptr);
  gfin_kernel<<<(E + 15) / 16, 256, 0, stream>>>(
      E, rptr_e, eids_e, srcs_e, sgE, dgduE, suE, egpB,
      (const float*)d_in[15], (const float*)d_in[16], ex, ea_out);

  // --- Layer 2 (bond graph; attr = ea from d_out, f32 stream) ---
  proj_kernel<true><<<gN, 256, 0, stream>>>(
      N, ntN, x, wt + 5 * 16384, biasF + 384, sgN, dgduN, suN);
  proj_kernel<false><<<gE, 256, 0, stream>>>(
      E, ntE, ea_out, wt + 7 * 16384, nullptr, egpB, nullptr, nullptr);
  gfin_kernel<<<(N + 15) / 16, 256, 0, stream>>>(
      N, rptr_n, eids_n, srcs_n, sgN, dgduN, suN, egpB,
      (const float*)d_in[27], (const float*)d_in[28], x, xn_out);
}

// Round 2
// 1042.343 us; speedup vs baseline: 1.2316x; 1.2316x over previous
//
#include <hip/hip_runtime.h>
#include <stdint.h>

#define DD 128

typedef __bf16 bf16x8 __attribute__((ext_vector_type(8)));
typedef float f32x4 __attribute__((ext_vector_type(4)));
typedef unsigned short u16;
typedef u16 u16x8 __attribute__((ext_vector_type(8)));

// Plain cast -> single HW cvt instruction (RNE), vs ~5 VALU ops manual.
__device__ __forceinline__ u16 f2bf(float f) {
  union { __bf16 h; u16 u; } v; v.h = (__bf16)f; return v.u;
}
__device__ __forceinline__ float bf2f(u16 b) {
  union { uint32_t u; float f; } v; v.u = (uint32_t)b << 16; return v.f;
}
__device__ __forceinline__ float silu_f(float x) {
  return x / (1.0f + __expf(-x));
}
__device__ __forceinline__ uint32_t pkbf(float lo, float hi) {
  return (uint32_t)f2bf(lo) | ((uint32_t)f2bf(hi) << 16);
}

// ---- f32 A staging (streamed): issue to regs / bf16-convert into LDS ----
// LDS layout: Ab[row*128 + ((cc ^ (row&7))<<3) + (k&7)]  (cc = k>>3).
// 512-thread block: each thread stages 4 x 32B (32 VGPRs held, no split --
// the r9 failure mode was SPLITTING the prefetch under a VGPR cap).
struct ARegs { float4 v[4][2]; };

__device__ __forceinline__ void issue_A(ARegs& r, const float* __restrict__ src,
                                        int base, int M, int tid) {
#pragma unroll
  for (int i = 0; i < 4; ++i) {
    int id = tid + (i << 9);
    int row = id >> 4;
    int cc = id & 15;
    if (base + row < M) {
      const float4* p = (const float4*)(src + (size_t)(base + row) * DD + cc * 8);
      r.v[i][0] = p[0]; r.v[i][1] = p[1];
    } else {
      r.v[i][0] = make_float4(0.f, 0.f, 0.f, 0.f);
      r.v[i][1] = make_float4(0.f, 0.f, 0.f, 0.f);
    }
  }
}

__device__ __forceinline__ void write_A(u16* Ab, const ARegs& r, int tid) {
#pragma unroll
  for (int i = 0; i < 4; ++i) {
    int id = tid + (i << 9);
    int row = id >> 4;
    int cc = id & 15;
    u16x8 o;
    o[0] = f2bf(r.v[i][0].x); o[1] = f2bf(r.v[i][0].y);
    o[2] = f2bf(r.v[i][0].z); o[3] = f2bf(r.v[i][0].w);
    o[4] = f2bf(r.v[i][1].x); o[5] = f2bf(r.v[i][1].y);
    o[6] = f2bf(r.v[i][1].z); o[7] = f2bf(r.v[i][1].w);
    *(u16x8*)&Ab[row * DD + ((cc ^ (row & 7)) << 3)] = o;
  }
}

// ---- MFMA stage. B fragments direct from global (L2-resident wt[n][k] bf16).
// Same lane->k bijection on A and B so any hw k-permutation cancels.
// Wave tile 32x64: acc[2][4] (32 AGPR/wave, half of round-0's 64).
__device__ __forceinline__ void mma_stage(const u16* Ab, const u16* __restrict__ wt,
                                          f32x4 acc[2][4], int lane, int wr, int wc) {
  int g = lane >> 4, r15 = lane & 15, s = r15 & 7;
  const u16* wbase = wt + (size_t)(wc * 64 + r15) * DD;
#pragma unroll
  for (int kk = 0; kk < 4; ++kk) {
    int ko = ((kk << 2) | g) << 3;
    bf16x8 bfr[4];
#pragma unroll
    for (int n = 0; n < 4; ++n)
      bfr[n] = *(const bf16x8*)&wbase[n * 16 * DD + ko];
    bf16x8 af[2];
#pragma unroll
    for (int m = 0; m < 2; ++m) {
      int rr = wr * 32 + m * 16 + r15;
      af[m] = *(const bf16x8*)&Ab[rr * DD + ((((kk << 2) | g) ^ s) << 3)];
    }
#pragma unroll
    for (int m = 0; m < 2; ++m)
#pragma unroll
      for (int n = 0; n < 4; ++n)
        acc[m][n] = __builtin_amdgcn_mfma_f32_16x16x32_bf16(af[m], bfr[n], acc[m][n], 0, 0, 0);
  }
}

// acc init with per-column bias folded in (C-in of first MFMA). col = wc*64+n*16+l15,
// identical for all 4 j-rows of a reg -> one splat per n. bias==null -> zeros.
__device__ __forceinline__ void init_acc(f32x4 a[2][4], const float* __restrict__ bias,
                                         int lane, int wc) {
  int l15 = lane & 15;
#pragma unroll
  for (int n = 0; n < 4; ++n) {
    float b = bias ? bias[wc * 64 + n * 16 + l15] : 0.f;
    f32x4 v = {b, b, b, b};
#pragma unroll
    for (int m = 0; m < 2; ++m) a[m][n] = v;
  }
}

// C/D: col=lane&15, row=(lane>>4)*4+reg. shfl-pair -> u32 per 2 cols; store
// to out[row*rs + co + col]. (bias pre-folded into acc init.)
__device__ __forceinline__ void store_acc(const f32x4 acc[2][4], u16* __restrict__ out,
                                          size_t rs, int co, int base, int M,
                                          int lane, int wr, int wc) {
  int l15 = lane & 15;
  bool oddl = lane & 1;
#pragma unroll
  for (int m = 0; m < 2; ++m) {
    int rb = wr * 32 + m * 16 + ((lane >> 4) << 2);
#pragma unroll
    for (int j = 0; j < 4; ++j) {
      int row = rb + j;
      bool act = (base + row < M);
      size_t rowoff = (size_t)(base + row) * rs + co;
#pragma unroll
      for (int n0 = 0; n0 < 4; n0 += 2) {
        int c0 = wc * 64 + n0 * 16 + l15;
        float v0 = acc[m][n0][j];
        float v1 = acc[m][n0 + 1][j];
        float t0 = __shfl_xor(v0, 1);
        float t1 = __shfl_xor(v1, 1);
        uint32_t pk = oddl ? pkbf(t1, v1) : pkbf(v0, t0);
        int col2 = oddl ? (c0 + 15) : c0;
        if (act) *(uint32_t*)&out[rowoff + col2] = pk;
      }
    }
  }
}

// ================= projection GEMMs (pure streaming, no gathers/atomics) ====
// One 128-row tile per block (short-lived blocks keep the L2/L3 window tight:
// the round-1 persistent grid-stride version tripled HBM traffic via per-XCD
// L2 thrash -- FETCH 129->840 MB). Latency is instead hidden with 2x wave
// parallelism: 512-thread blocks, 32x64 wave tile, (512,4) -> 16 waves/CU.
template <bool FOUR>
__global__ void __launch_bounds__(512, 4) proj_kernel(
    int M, const float* __restrict__ src, const u16* __restrict__ wt,
    const float* __restrict__ bF,  // folded biases [3][128]: sg+dg+eg, du, su
    u16* __restrict__ o_sg, u16* __restrict__ o_dgdu, u16* __restrict__ o_su) {
  __shared__ u16 Ab[128 * DD];  // 32 KB
  int tid = threadIdx.x, lane = tid & 63, wid = tid >> 6;
  int wr = wid >> 1, wc = wid & 1;
  int base = blockIdx.x * 128;
  {
    ARegs ar;
    issue_A(ar, src, base, M, tid);
    write_A(Ab, ar, tid);
  }
  __syncthreads();
  f32x4 acc[2][4];
  init_acc(acc, FOUR ? bF : nullptr, lane, wc);
  mma_stage(Ab, wt + 0 * 16384, acc, lane, wr, wc);        // sg (or egp)
  store_acc(acc, o_sg, DD, 0, base, M, lane, wr, wc);
  if (FOUR) {
    init_acc(acc, nullptr, lane, wc);
    mma_stage(Ab, wt + 1 * 16384, acc, lane, wr, wc);      // dg (bias in sg)
    store_acc(acc, o_dgdu, 2 * DD, 0, base, M, lane, wr, wc);
    init_acc(acc, bF + 128, lane, wc);
    mma_stage(Ab, wt + 3 * 16384, acc, lane, wr, wc);      // du + bdu
    store_acc(acc, o_dgdu, 2 * DD, DD, base, M, lane, wr, wc);
    init_acc(acc, bF + 256, lane, wc);
    mma_stage(Ab, wt + 4 * 16384, acc, lane, wr, wc);      // su + bsu
    store_acc(acc, o_su, DD, 0, base, M, lane, wr, wc);
  }
}

// ================= CSR build =================
__global__ void __launch_bounds__(256) hist_kernel(const int* __restrict__ dst,
                                                   int Me, int* __restrict__ cnt) {
  int i = blockIdx.x * blockDim.x + threadIdx.x;
  if (i < Me) atomicAdd(&cnt[dst[i]], 1);
}

__global__ void __launch_bounds__(256) scan1_kernel(const int* __restrict__ cnt, int M,
                                                    int* __restrict__ out,
                                                    int* __restrict__ bsum) {
  __shared__ int sh[256];
  int t = threadIdx.x;
  int i0 = blockIdx.x * 1024 + t * 4;
  int v[4];
#pragma unroll
  for (int k = 0; k < 4; ++k) v[k] = (i0 + k < M) ? cnt[i0 + k] : 0;
  int s = v[0] + v[1] + v[2] + v[3];
  sh[t] = s;
  __syncthreads();
#pragma unroll
  for (int off = 1; off < 256; off <<= 1) {
    int x = (t >= off) ? sh[t - off] : 0;
    __syncthreads();
    sh[t] += x;
    __syncthreads();
  }
  int run = sh[t] - s;  // exclusive
  if (t == 255) bsum[blockIdx.x] = sh[255];
#pragma unroll
  for (int k = 0; k < 4; ++k) {
    if (i0 + k < M) out[i0 + k] = run;
    run += v[k];
  }
}

__global__ void __launch_bounds__(256) scan2_kernel(int* __restrict__ bsum, int NB) {
  __shared__ int sh[512];
  int t = threadIdx.x;
  for (int i = t; i < 512; i += 256) sh[i] = (i < NB) ? bsum[i] : 0;
  __syncthreads();
  for (int off = 1; off < 512; off <<= 1) {
    int tmp[2];
#pragma unroll
    for (int q = 0; q < 2; ++q) {
      int i = t + q * 256;
      tmp[q] = (i >= off) ? sh[i - off] : 0;
    }
    __syncthreads();
#pragma unroll
    for (int q = 0; q < 2; ++q) sh[t + q * 256] += tmp[q];
    __syncthreads();
  }
  for (int i = t; i < NB; i += 256) bsum[i] = (i == 0) ? 0 : sh[i - 1];
}

__global__ void __launch_bounds__(256) scan3_kernel(int* __restrict__ rowptr,
                                                    const int* __restrict__ bscan,
                                                    int M, int Medges,
                                                    int* __restrict__ head) {
  int i = blockIdx.x * blockDim.x + threadIdx.x;
  if (i < M) {
    int v = rowptr[i] + bscan[i >> 10];
    rowptr[i] = v;
    head[i] = v;
  }
  if (i == 0) rowptr[M] = Medges;
}

// Counting-sort: slot s gets edge id + its src (4B scatters on L2-resident arrays).
__global__ void __launch_bounds__(256) eid_kernel(const int* __restrict__ src,
                                                  const int* __restrict__ dst, int Me,
                                                  int* __restrict__ head,
                                                  int* __restrict__ eids,
                                                  int* __restrict__ srcs) {
  int i = blockIdx.x * blockDim.x + threadIdx.x;
  if (i < Me) {
    int s = atomicAdd(&head[dst[i]], 1);
    eids[s] = i;
    srcs[s] = src[i];
  }
}

// ================= misc prep =================
// W (k-major [128][128] f32) -> wt[n*128+k] bf16.
__global__ void prep_weights(const float* __restrict__ w0, const float* __restrict__ w1,
                             const float* __restrict__ w2, const float* __restrict__ w3,
                             const float* __restrict__ w4, const float* __restrict__ w5,
                             const float* __restrict__ w6, const float* __restrict__ w7,
                             const float* __restrict__ w8, const float* __restrict__ w9,
                             u16* __restrict__ wt) {
  const float* W;
  switch (blockIdx.x) {
    case 0: W = w0; break; case 1: W = w1; break; case 2: W = w2; break;
    case 3: W = w3; break; case 4: W = w4; break; case 5: W = w5; break;
    case 6: W = w6; break; case 7: W = w7; break; case 8: W = w8; break;
    default: W = w9; break;
  }
  u16* dst = wt + blockIdx.x * 16384;
  for (int o = threadIdx.x; o < 16384; o += 256) {
    int n = o >> 7, k = o & 127;
    dst[o] = f2bf(W[k * DD + n]);
  }
}

// Folded bias table: [0..2]*128 = eu {sg+dg+eg, du, su}; [3..5]*128 = nu same.
__global__ void fold_bias(const float* __restrict__ e_sg, const float* __restrict__ e_dg,
                          const float* __restrict__ e_eg, const float* __restrict__ e_du,
                          const float* __restrict__ e_su,
                          const float* __restrict__ n_sg, const float* __restrict__ n_dg,
                          const float* __restrict__ n_eg, const float* __restrict__ n_du,
                          const float* __restrict__ n_su, float* __restrict__ out) {
  int i = threadIdx.x;
  if (i < 128) {
    out[i]        = e_sg[i] + e_dg[i] + e_eg[i];
    out[128 + i]  = e_du[i];
    out[256 + i]  = e_su[i];
    out[384 + i]  = n_sg[i] + n_dg[i] + n_eg[i];
    out[512 + i]  = n_du[i];
    out[640 + i]  = n_su[i];
  }
}

// ============ gather-finalize: 16 lanes/row, 8 cols/lane, 4 rows/wave ========
// per row r: for s in [rptr[r],rptr[r+1]):
//   e=eids[s], sv=srcs[s]
//   gate = silu(sg'[r] + dg[sv] + egp[e]); ax += gate * du'[sv]
// vx = su'[r] + ax; LN; silu; + resid(f32); write f32 out.
// (biases pre-folded: sg' = sg+bsg+bdg+beg, du' = du+bdu, su' = su+bsu)
__global__ void __launch_bounds__(256) gfin_kernel(
    int M, const int* __restrict__ rptr, const int* __restrict__ eids,
    const int* __restrict__ srcs,
    const u16* __restrict__ sg_t, const u16* __restrict__ dgdu_t,
    const u16* __restrict__ su_t, const u16* __restrict__ egp,
    const float* __restrict__ gamma, const float* __restrict__ beta,
    const float* __restrict__ resid, float* __restrict__ out) {
  int gtid = blockIdx.x * blockDim.x + threadIdx.x;
  int r = gtid >> 4;
  int l16 = gtid & 15;
  if (r >= M) return;
  int c = l16 * 8;

  u16x8 sgp = *(const u16x8*)&sg_t[(size_t)r * DD + c];
  float sg[8], ax[8];
#pragma unroll
  for (int k = 0; k < 8; ++k) { sg[k] = bf2f(sgp[k]); ax[k] = 0.f; }

  int segb = rptr[r], sege = rptr[r + 1];
  for (int s = segb; s < sege; ++s) {
    int e = eids[s];
    int sv = srcs[s];
    u16x8 gp = *(const u16x8*)&egp[(size_t)e * DD + c];
    u16x8 dgp = *(const u16x8*)&dgdu_t[(size_t)sv * (2 * DD) + c];
    u16x8 dup = *(const u16x8*)&dgdu_t[(size_t)sv * (2 * DD) + DD + c];
#pragma unroll
    for (int k = 0; k < 8; ++k) {
      float g = silu_f(sg[k] + bf2f(dgp[k]) + bf2f(gp[k]));
      ax[k] += g * bf2f(dup[k]);
    }
  }

  u16x8 sup = *(const u16x8*)&su_t[(size_t)r * DD + c];
  float v[8];
  float sum = 0.f;
#pragma unroll
  for (int k = 0; k < 8; ++k) { v[k] = bf2f(sup[k]) + ax[k]; sum += v[k]; }
#pragma unroll
  for (int off = 1; off <= 8; off <<= 1) sum += __shfl_xor(sum, off);
  float mean = sum * (1.0f / 128.0f);
  float sq = 0.f;
#pragma unroll
  for (int k = 0; k < 8; ++k) { v[k] -= mean; sq += v[k] * v[k]; }
#pragma unroll
  for (int off = 1; off <= 8; off <<= 1) sq += __shfl_xor(sq, off);
  float rs = rsqrtf(sq * (1.0f / 128.0f) + 1e-5f);

  float4 gm0 = *(const float4*)&gamma[c];
  float4 gm1 = *(const float4*)&gamma[c + 4];
  float4 bt0 = *(const float4*)&beta[c];
  float4 bt1 = *(const float4*)&beta[c + 4];
  float4 rr0 = *(const float4*)&resid[(size_t)r * DD + c];
  float4 rr1 = *(const float4*)&resid[(size_t)r * DD + c + 4];
  float gmv[8] = {gm0.x, gm0.y, gm0.z, gm0.w, gm1.x, gm1.y, gm1.z, gm1.w};
  float btv[8] = {bt0.x, bt0.y, bt0.z, bt0.w, bt1.x, bt1.y, bt1.z, bt1.w};
  float rrv[8] = {rr0.x, rr0.y, rr0.z, rr0.w, rr1.x, rr1.y, rr1.z, rr1.w};
  float o[8];
#pragma unroll
  for (int k = 0; k < 8; ++k)
    o[k] = silu_f(v[k] * rs * gmv[k] + btv[k]) + rrv[k];
  float4 o0 = {o[0], o[1], o[2], o[3]};
  float4 o1 = {o[4], o[5], o[6], o[7]};
  *(float4*)&out[(size_t)r * DD + c] = o0;
  *(float4*)&out[(size_t)r * DD + c + 4] = o1;
}

extern "C" void kernel_launch(void* const* d_in, const int* in_sizes, int n_in,
                              void* d_out, int out_size, void* d_ws, size_t ws_size,
                              hipStream_t stream) {
  const float* x   = (const float*)d_in[0];
  const float* ex  = (const float*)d_in[1];
  const float* lga = (const float*)d_in[2];
  const int* gei   = (const int*)d_in[3];
  const int* lgei  = (const int*)d_in[4];
  int N   = in_sizes[0] / DD;
  int E   = in_sizes[3] / 2;
  int ELG = in_sizes[4] / 2;

  char* p = (char*)d_ws;
  size_t off = 0;
  auto alloc = [&](size_t bytes) { char* q = p + off; off += (bytes + 255) & ~255ull; return q; };

  u16* wt     = (u16*)alloc((size_t)10 * 16384 * 2);
  float* biasF = (float*)alloc(768 * 4);
  u16* sgE    = (u16*)alloc((size_t)E * DD * 2);        // 128 MB
  u16* dgduE  = (u16*)alloc((size_t)E * 2 * DD * 2);    // 256 MB
  u16* suE    = (u16*)alloc((size_t)E * DD * 2);        // 128 MB
  int  maxME  = (ELG > E) ? ELG : E;
  u16* egpB   = (u16*)alloc((size_t)maxME * DD * 2);    // 128 MB, shared L1/L2
  u16* sgN    = (u16*)alloc((size_t)N * DD * 2);
  u16* dgduN  = (u16*)alloc((size_t)N * 2 * DD * 2);
  u16* suN    = (u16*)alloc((size_t)N * DD * 2);
  int* cnt_e  = (int*)alloc((size_t)E * 4);
  int* rptr_e = (int*)alloc((size_t)(E + 1) * 4);
  int* head_e = (int*)alloc((size_t)E * 4);
  int* eids_e = (int*)alloc((size_t)ELG * 4);
  int* srcs_e = (int*)alloc((size_t)ELG * 4);
  int* cnt_n  = (int*)alloc((size_t)N * 4);
  int* rptr_n = (int*)alloc((size_t)(N + 1) * 4);
  int* head_n = (int*)alloc((size_t)N * 4);
  int* eids_n = (int*)alloc((size_t)E * 4);
  int* srcs_n = (int*)alloc((size_t)E * 4);
  int* bsum   = (int*)alloc(512 * 4);
  if (ws_size < off) return;  // visible failure if ws too small

  float* xn_out = (float*)d_out;
  float* ea_out = (float*)d_out + (size_t)N * DD;

  // --- prep: weights + folded biases ---
  // wt slots 0..9 = eu{sg,dg,eg,du,su}, nu{sg,dg,eg,du,su}
  prep_weights<<<10, 256, 0, stream>>>(
      (const float*)d_in[5], (const float*)d_in[7], (const float*)d_in[9],
      (const float*)d_in[13], (const float*)d_in[11],
      (const float*)d_in[17], (const float*)d_in[19], (const float*)d_in[21],
      (const float*)d_in[25], (const float*)d_in[23], wt);
  fold_bias<<<1, 128, 0, stream>>>(
      (const float*)d_in[6], (const float*)d_in[8], (const float*)d_in[10],
      (const float*)d_in[14], (const float*)d_in[12],
      (const float*)d_in[18], (const float*)d_in[20], (const float*)d_in[22],
      (const float*)d_in[26], (const float*)d_in[24], biasF);

  // --- CSR builds: counts -> rowptr -> (eid, src) counting-sort ---
  hipMemsetAsync(cnt_e, 0, (size_t)E * 4, stream);
  hipMemsetAsync(cnt_n, 0, (size_t)N * 4, stream);
  hist_kernel<<<(ELG + 255) / 256, 256, 0, stream>>>(lgei + ELG, ELG, cnt_e);
  hist_kernel<<<(E + 255) / 256, 256, 0, stream>>>(gei + E, E, cnt_n);

  int NBe = (E + 1023) / 1024;
  scan1_kernel<<<NBe, 256, 0, stream>>>(cnt_e, E, rptr_e, bsum);
  scan2_kernel<<<1, 256, 0, stream>>>(bsum, NBe);
  scan3_kernel<<<(E + 255) / 256, 256, 0, stream>>>(rptr_e, bsum, E, ELG, head_e);
  eid_kernel<<<(ELG + 255) / 256, 256, 0, stream>>>(lgei, lgei + ELG, ELG, head_e,
                                                    eids_e, srcs_e);

  int NBn = (N + 1023) / 1024;
  scan1_kernel<<<NBn, 256, 0, stream>>>(cnt_n, N, rptr_n, bsum);
  scan2_kernel<<<1, 256, 0, stream>>>(bsum, NBn);
  scan3_kernel<<<(N + 255) / 256, 256, 0, stream>>>(rptr_n, bsum, N, E, head_n);
  eid_kernel<<<(E + 255) / 256, 256, 0, stream>>>(gei, gei + E, E, head_n,
                                                  eids_n, srcs_n);

  // --- Layer 1 (line graph; rows = g's edges) ---
  proj_kernel<true><<<(E + 127) / 128, 512, 0, stream>>>(
      E, ex, wt, biasF, sgE, dgduE, suE);
  proj_kernel<false><<<(ELG + 127) / 128, 512, 0, stream>>>(
      ELG, lga, wt + 2 * 16384, nullptr, egpB, nullptr, nullptr);
  gfin_kernel<<<(E + 15) / 16, 256, 0, stream>>>(
      E, rptr_e, eids_e, srcs_e, sgE, dgduE, suE, egpB,
      (const float*)d_in[15], (const float*)d_in[16], ex, ea_out);

  // --- Layer 2 (bond graph; attr = ea from d_out, f32 stream) ---
  proj_kernel<true><<<(N + 127) / 128, 512, 0, stream>>>(
      N, x, wt + 5 * 16384, biasF + 384, sgN, dgduN, suN);
  proj_kernel<false><<<(E + 127) / 128, 512, 0, stream>>>(
      E, ea_out, wt + 7 * 16384, nullptr, egpB, nullptr, nullptr);
  gfin_kernel<<<(N + 15) / 16, 256, 0, stream>>>(
      N, rptr_n, eids_n, srcs_n, sgN, dgduN, suN, egpB,
      (const float*)d_in[27], (const float*)d_in[28], x, xn_out);
}

// Round 4
// 962.780 us; speedup vs baseline: 1.3333x; 1.0826x over previous
//
#include <hip/hip_runtime.h>
#include <stdint.h>

#define DD 128

typedef __bf16 bf16x8 __attribute__((ext_vector_type(8)));
typedef float f32x4 __attribute__((ext_vector_type(4)));
typedef unsigned short u16;
typedef u16 u16x8 __attribute__((ext_vector_type(8)));

// Plain cast -> single HW cvt instruction (RNE), vs ~5 VALU ops manual.
__device__ __forceinline__ u16 f2bf(float f) {
  union { __bf16 h; u16 u; } v; v.h = (__bf16)f; return v.u;
}
__device__ __forceinline__ float bf2f(u16 b) {
  union { uint32_t u; float f; } v; v.u = (uint32_t)b << 16; return v.f;
}
__device__ __forceinline__ float silu_f(float x) {
  return x / (1.0f + __expf(-x));
}
__device__ __forceinline__ uint32_t pkbf(float lo, float hi) {
  return (uint32_t)f2bf(lo) | ((uint32_t)f2bf(hi) << 16);
}

// ---- f32 A staging (streamed): issue to regs / bf16-convert into LDS ----
// LDS layout: Ab[row*128 + ((cc ^ (row&7))<<3) + (k&7)]  (cc = k>>3).
// NOTE: __builtin_nontemporal_load needs a plain vector type (ext_vector),
// HIP's float4 class is rejected -> ARegs uses f32x4.
struct ARegs { f32x4 v[8][2]; };

__device__ __forceinline__ void issue_A(ARegs& r, const float* __restrict__ src,
                                        int base, int M, int tid) {
#pragma unroll
  for (int i = 0; i < 8; ++i) {
    int id = tid + (i << 8);
    int row = id >> 4;
    int cc = id & 15;
    if (base + row < M) {
      const f32x4* p = (const f32x4*)(src + (size_t)(base + row) * DD + cc * 8);
      r.v[i][0] = __builtin_nontemporal_load(p);       // streamed, never reused
      r.v[i][1] = __builtin_nontemporal_load(p + 1);
    } else {
      r.v[i][0] = (f32x4){0.f, 0.f, 0.f, 0.f};
      r.v[i][1] = (f32x4){0.f, 0.f, 0.f, 0.f};
    }
  }
}

__device__ __forceinline__ void write_A(u16* Ab, const ARegs& r, int tid) {
#pragma unroll
  for (int i = 0; i < 8; ++i) {
    int id = tid + (i << 8);
    int row = id >> 4;
    int cc = id & 15;
    u16x8 o;
    o[0] = f2bf(r.v[i][0][0]); o[1] = f2bf(r.v[i][0][1]);
    o[2] = f2bf(r.v[i][0][2]); o[3] = f2bf(r.v[i][0][3]);
    o[4] = f2bf(r.v[i][1][0]); o[5] = f2bf(r.v[i][1][1]);
    o[6] = f2bf(r.v[i][1][2]); o[7] = f2bf(r.v[i][1][3]);
    *(u16x8*)&Ab[row * DD + ((cc ^ (row & 7)) << 3)] = o;
  }
}

// ---- B fragments preloaded to registers (64 VGPR per set). Loading the NEXT
// stage's set BEFORE the current stage's stores keeps stores in flight across
// the vmcnt wait (FIFO semantics: the B loads are older than the stores, so
// waiting for them leaves the stores outstanding). This was the stage-to-stage
// serializer: previously B loads followed 32 stores, so every B wait drained
// the whole store burst to L2.
struct BRegs { bf16x8 b[4][4]; };  // [kk][n]

__device__ __forceinline__ void load_B(BRegs& br, const u16* __restrict__ wt,
                                       int lane, int wc) {
  int g = lane >> 4, r15 = lane & 15;
  const u16* wbase = wt + (size_t)(wc * 64 + r15) * DD;
#pragma unroll
  for (int kk = 0; kk < 4; ++kk) {
    int ko = ((kk << 2) | g) << 3;
#pragma unroll
    for (int n = 0; n < 4; ++n)
      br.b[kk][n] = *(const bf16x8*)&wbase[n * 16 * DD + ko];
  }
}

// ---- MFMA stage from LDS A + register B. Same lane->k bijection on A and B
// so any hw k-permutation cancels.
__device__ __forceinline__ void mma_stage(const u16* Ab, const BRegs& br,
                                          f32x4 acc[4][4], int lane, int wr) {
  int g = lane >> 4, r15 = lane & 15, s = r15 & 7;
#pragma unroll
  for (int kk = 0; kk < 4; ++kk) {
    bf16x8 af[4];
#pragma unroll
    for (int m = 0; m < 4; ++m) {
      int rr = wr * 64 + m * 16 + r15;
      af[m] = *(const bf16x8*)&Ab[rr * DD + ((((kk << 2) | g) ^ s) << 3)];
    }
#pragma unroll
    for (int m = 0; m < 4; ++m)
#pragma unroll
      for (int n = 0; n < 4; ++n)
        acc[m][n] = __builtin_amdgcn_mfma_f32_16x16x32_bf16(af[m], br.b[kk][n], acc[m][n], 0, 0, 0);
  }
}

// acc init with per-column bias folded in (C-in of first MFMA). col = wc*64+n*16+l15,
// identical for all 4 j-rows of a reg -> one splat per n. bias==null -> zeros.
__device__ __forceinline__ void init_acc(f32x4 a[4][4], const float* __restrict__ bias,
                                         int lane, int wc) {
  int l15 = lane & 15;
#pragma unroll
  for (int n = 0; n < 4; ++n) {
    float b = bias ? bias[wc * 64 + n * 16 + l15] : 0.f;
    f32x4 v = {b, b, b, b};
#pragma unroll
    for (int m = 0; m < 4; ++m) a[m][n] = v;
  }
}

// C/D: col=lane&15, row=(lane>>4)*4+reg. shfl-pair -> u32 per 2 cols; store
// nontemporal (streaming 512 MB through L2 evicts everything useful).
__device__ __forceinline__ void store_acc(const f32x4 acc[4][4], u16* __restrict__ out,
                                          size_t rs, int co, int base, int M,
                                          int lane, int wr, int wc) {
  int l15 = lane & 15;
  bool oddl = lane & 1;
#pragma unroll
  for (int m = 0; m < 4; ++m) {
    int rb = wr * 64 + m * 16 + ((lane >> 4) << 2);
#pragma unroll
    for (int j = 0; j < 4; ++j) {
      int row = rb + j;
      bool act = (base + row < M);
      size_t rowoff = (size_t)(base + row) * rs + co;
#pragma unroll
      for (int n0 = 0; n0 < 4; n0 += 2) {
        int c0 = wc * 64 + n0 * 16 + l15;
        float v0 = acc[m][n0][j];
        float v1 = acc[m][n0 + 1][j];
        float t0 = __shfl_xor(v0, 1);
        float t1 = __shfl_xor(v1, 1);
        uint32_t pk = oddl ? pkbf(t1, v1) : pkbf(v0, t0);
        int col2 = oddl ? (c0 + 15) : c0;
        if (act) __builtin_nontemporal_store(pk, (uint32_t*)&out[rowoff + col2]);
      }
    }
  }
}

// ================= projection GEMMs (pure streaming, no gathers/atomics) ====
// One 128-row tile per block, 256 threads, 64x64 wave tile, (256,2) -- the
// round-0 shape (cleanest HBM traffic: 500 MB exact writes). Round-1
// persistent blocks and round-2 512-thread blocks both inflated traffic and
// regressed. This round keeps the shape and fixes the stage-to-stage vmcnt
// interlock (B prefetch to regs) + uses nt loads/stores for the streams.
template <bool FOUR>
__global__ void __launch_bounds__(256, 2) proj_kernel(
    int M, const float* __restrict__ src, const u16* __restrict__ wt,
    const float* __restrict__ bF,  // folded biases [3][128]: sg+dg+eg, du, su
    u16* __restrict__ o_sg, u16* __restrict__ o_dgdu, u16* __restrict__ o_su) {
  __shared__ u16 Ab[128 * DD];  // 32 KB
  int tid = threadIdx.x, lane = tid & 63, wid = tid >> 6;
  int wr = wid >> 1, wc = wid & 1;
  int base = blockIdx.x * 128;
  BRegs b0, b1;
  {
    ARegs ar;
    issue_A(ar, src, base, M, tid);   // HBM loads first (longest pole)
    load_B(b0, wt + 0 * 16384, lane, wc);  // L2 loads behind them
    write_A(Ab, ar, tid);             // waits A only (B newer in FIFO)
  }
  __syncthreads();
  f32x4 acc[4][4];
  init_acc(acc, FOUR ? bF : nullptr, lane, wc);
  mma_stage(Ab, b0, acc, lane, wr);                        // sg (or egp)
  if (FOUR) {
    load_B(b1, wt + 1 * 16384, lane, wc);    // before stores: stores stay in flight
    store_acc(acc, o_sg, DD, 0, base, M, lane, wr, wc);
    init_acc(acc, nullptr, lane, wc);
    mma_stage(Ab, b1, acc, lane, wr);                      // dg (bias in sg)
    load_B(b0, wt + 3 * 16384, lane, wc);
    store_acc(acc, o_dgdu, 2 * DD, 0, base, M, lane, wr, wc);
    init_acc(acc, bF + 128, lane, wc);
    mma_stage(Ab, b0, acc, lane, wr);                      // du + bdu
    load_B(b1, wt + 4 * 16384, lane, wc);
    store_acc(acc, o_dgdu, 2 * DD, DD, base, M, lane, wr, wc);
    init_acc(acc, bF + 256, lane, wc);
    mma_stage(Ab, b1, acc, lane, wr);                      // su + bsu
    store_acc(acc, o_su, DD, 0, base, M, lane, wr, wc);
  } else {
    store_acc(acc, o_sg, DD, 0, base, M, lane, wr, wc);
  }
}

// ================= CSR build =================
__global__ void __launch_bounds__(256) hist_kernel(const int* __restrict__ dst,
                                                   int Me, int* __restrict__ cnt) {
  int i = blockIdx.x * blockDim.x + threadIdx.x;
  if (i < Me) atomicAdd(&cnt[dst[i]], 1);
}

__global__ void __launch_bounds__(256) scan1_kernel(const int* __restrict__ cnt, int M,
                                                    int* __restrict__ out,
                                                    int* __restrict__ bsum) {
  __shared__ int sh[256];
  int t = threadIdx.x;
  int i0 = blockIdx.x * 1024 + t * 4;
  int v[4];
#pragma unroll
  for (int k = 0; k < 4; ++k) v[k] = (i0 + k < M) ? cnt[i0 + k] : 0;
  int s = v[0] + v[1] + v[2] + v[3];
  sh[t] = s;
  __syncthreads();
#pragma unroll
  for (int off = 1; off < 256; off <<= 1) {
    int x = (t >= off) ? sh[t - off] : 0;
    __syncthreads();
    sh[t] += x;
    __syncthreads();
  }
  int run = sh[t] - s;  // exclusive
  if (t == 255) bsum[blockIdx.x] = sh[255];
#pragma unroll
  for (int k = 0; k < 4; ++k) {
    if (i0 + k < M) out[i0 + k] = run;
    run += v[k];
  }
}

__global__ void __launch_bounds__(256) scan2_kernel(int* __restrict__ bsum, int NB) {
  __shared__ int sh[512];
  int t = threadIdx.x;
  for (int i = t; i < 512; i += 256) sh[i] = (i < NB) ? bsum[i] : 0;
  __syncthreads();
  for (int off = 1; off < 512; off <<= 1) {
    int tmp[2];
#pragma unroll
    for (int q = 0; q < 2; ++q) {
      int i = t + q * 256;
      tmp[q] = (i >= off) ? sh[i - off] : 0;
    }
    __syncthreads();
#pragma unroll
    for (int q = 0; q < 2; ++q) sh[t + q * 256] += tmp[q];
    __syncthreads();
  }
  for (int i = t; i < NB; i += 256) bsum[i] = (i == 0) ? 0 : sh[i - 1];
}

__global__ void __launch_bounds__(256) scan3_kernel(int* __restrict__ rowptr,
                                                    const int* __restrict__ bscan,
                                                    int M, int Medges,
                                                    int* __restrict__ head) {
  int i = blockIdx.x * blockDim.x + threadIdx.x;
  if (i < M) {
    int v = rowptr[i] + bscan[i >> 10];
    rowptr[i] = v;
    head[i] = v;
  }
  if (i == 0) rowptr[M] = Medges;
}

// Counting-sort: slot s gets edge id + its src (4B scatters on L2-resident arrays).
__global__ void __launch_bounds__(256) eid_kernel(const int* __restrict__ src,
                                                  const int* __restrict__ dst, int Me,
                                                  int* __restrict__ head,
                                                  int* __restrict__ eids,
                                                  int* __restrict__ srcs) {
  int i = blockIdx.x * blockDim.x + threadIdx.x;
  if (i < Me) {
    int s = atomicAdd(&head[dst[i]], 1);
    eids[s] = i;
    srcs[s] = src[i];
  }
}

// ================= misc prep =================
// W (k-major [128][128] f32) -> wt[n*128+k] bf16.
__global__ void prep_weights(const float* __restrict__ w0, const float* __restrict__ w1,
                             const float* __restrict__ w2, const float* __restrict__ w3,
                             const float* __restrict__ w4, const float* __restrict__ w5,
                             const float* __restrict__ w6, const float* __restrict__ w7,
                             const float* __restrict__ w8, const float* __restrict__ w9,
                             u16* __restrict__ wt) {
  const float* W;
  switch (blockIdx.x) {
    case 0: W = w0; break; case 1: W = w1; break; case 2: W = w2; break;
    case 3: W = w3; break; case 4: W = w4; break; case 5: W = w5; break;
    case 6: W = w6; break; case 7: W = w7; break; case 8: W = w8; break;
    default: W = w9; break;
  }
  u16* dst = wt + blockIdx.x * 16384;
  for (int o = threadIdx.x; o < 16384; o += 256) {
    int n = o >> 7, k = o & 127;
    dst[o] = f2bf(W[k * DD + n]);
  }
}

// Folded bias table: [0..2]*128 = eu {sg+dg+eg, du, su}; [3..5]*128 = nu same.
__global__ void fold_bias(const float* __restrict__ e_sg, const float* __restrict__ e_dg,
                          const float* __restrict__ e_eg, const float* __restrict__ e_du,
                          const float* __restrict__ e_su,
                          const float* __restrict__ n_sg, const float* __restrict__ n_dg,
                          const float* __restrict__ n_eg, const float* __restrict__ n_du,
                          const float* __restrict__ n_su, float* __restrict__ out) {
  int i = threadIdx.x;
  if (i < 128) {
    out[i]        = e_sg[i] + e_dg[i] + e_eg[i];
    out[128 + i]  = e_du[i];
    out[256 + i]  = e_su[i];
    out[384 + i]  = n_sg[i] + n_dg[i] + n_eg[i];
    out[512 + i]  = n_du[i];
    out[640 + i]  = n_su[i];
  }
}

// ============ gather-finalize: 16 lanes/row, 8 cols/lane, 4 rows/wave ========
// per row r: for s in [rptr[r],rptr[r+1]):
//   e=eids[s], sv=srcs[s]
//   gate = silu(sg'[r] + dg[sv] + egp[e]); ax += gate * du'[sv]
// vx = su'[r] + ax; LN; silu; + resid(f32); write f32 out.
// (biases pre-folded: sg' = sg+bsg+bdg+beg, du' = du+bdu, su' = su+bsu)
__global__ void __launch_bounds__(256) gfin_kernel(
    int M, const int* __restrict__ rptr, const int* __restrict__ eids,
    const int* __restrict__ srcs,
    const u16* __restrict__ sg_t, const u16* __restrict__ dgdu_t,
    const u16* __restrict__ su_t, const u16* __restrict__ egp,
    const float* __restrict__ gamma, const float* __restrict__ beta,
    const float* __restrict__ resid, float* __restrict__ out) {
  int gtid = blockIdx.x * blockDim.x + threadIdx.x;
  int r = gtid >> 4;
  int l16 = gtid & 15;
  if (r >= M) return;
  int c = l16 * 8;

  u16x8 sgp = *(const u16x8*)&sg_t[(size_t)r * DD + c];
  float sg[8], ax[8];
#pragma unroll
  for (int k = 0; k < 8; ++k) { sg[k] = bf2f(sgp[k]); ax[k] = 0.f; }

  int segb = rptr[r], sege = rptr[r + 1];
  for (int s = segb; s < sege; ++s) {
    int e = eids[s];
    int sv = srcs[s];
    u16x8 gp = *(const u16x8*)&egp[(size_t)e * DD + c];
    u16x8 dgp = *(const u16x8*)&dgdu_t[(size_t)sv * (2 * DD) + c];
    u16x8 dup = *(const u16x8*)&dgdu_t[(size_t)sv * (2 * DD) + DD + c];
#pragma unroll
    for (int k = 0; k < 8; ++k) {
      float g = silu_f(sg[k] + bf2f(dgp[k]) + bf2f(gp[k]));
      ax[k] += g * bf2f(dup[k]);
    }
  }

  u16x8 sup = *(const u16x8*)&su_t[(size_t)r * DD + c];
  float v[8];
  float sum = 0.f;
#pragma unroll
  for (int k = 0; k < 8; ++k) { v[k] = bf2f(sup[k]) + ax[k]; sum += v[k]; }
#pragma unroll
  for (int off = 1; off <= 8; off <<= 1) sum += __shfl_xor(sum, off);
  float mean = sum * (1.0f / 128.0f);
  float sq = 0.f;
#pragma unroll
  for (int k = 0; k < 8; ++k) { v[k] -= mean; sq += v[k] * v[k]; }
#pragma unroll
  for (int off = 1; off <= 8; off <<= 1) sq += __shfl_xor(sq, off);
  float rs = rsqrtf(sq * (1.0f / 128.0f) + 1e-5f);

  float4 gm0 = *(const float4*)&gamma[c];
  float4 gm1 = *(const float4*)&gamma[c + 4];
  float4 bt0 = *(const float4*)&beta[c];
  float4 bt1 = *(const float4*)&beta[c + 4];
  float4 rr0 = *(const float4*)&resid[(size_t)r * DD + c];
  float4 rr1 = *(const float4*)&resid[(size_t)r * DD + c + 4];
  float gmv[8] = {gm0.x, gm0.y, gm0.z, gm0.w, gm1.x, gm1.y, gm1.z, gm1.w};
  float btv[8] = {bt0.x, bt0.y, bt0.z, bt0.w, bt1.x, bt1.y, bt1.z, bt1.w};
  float rrv[8] = {rr0.x, rr0.y, rr0.z, rr0.w, rr1.x, rr1.y, rr1.z, rr1.w};
  float o[8];
#pragma unroll
  for (int k = 0; k < 8; ++k)
    o[k] = silu_f(v[k] * rs * gmv[k] + btv[k]) + rrv[k];
  float4 o0 = {o[0], o[1], o[2], o[3]};
  float4 o1 = {o[4], o[5], o[6], o[7]};
  *(float4*)&out[(size_t)r * DD + c] = o0;
  *(float4*)&out[(size_t)r * DD + c + 4] = o1;
}

extern "C" void kernel_launch(void* const* d_in, const int* in_sizes, int n_in,
                              void* d_out, int out_size, void* d_ws, size_t ws_size,
                              hipStream_t stream) {
  const float* x   = (const float*)d_in[0];
  const float* ex  = (const float*)d_in[1];
  const float* lga = (const float*)d_in[2];
  const int* gei   = (const int*)d_in[3];
  const int* lgei  = (const int*)d_in[4];
  int N   = in_sizes[0] / DD;
  int E   = in_sizes[3] / 2;
  int ELG = in_sizes[4] / 2;

  char* p = (char*)d_ws;
  size_t off = 0;
  auto alloc = [&](size_t bytes) { char* q = p + off; off += (bytes + 255) & ~255ull; return q; };

  u16* wt     = (u16*)alloc((size_t)10 * 16384 * 2);
  float* biasF = (float*)alloc(768 * 4);
  u16* sgE    = (u16*)alloc((size_t)E * DD * 2);        // 128 MB
  u16* dgduE  = (u16*)alloc((size_t)E * 2 * DD * 2);    // 256 MB
  u16* suE    = (u16*)alloc((size_t)E * DD * 2);        // 128 MB
  int  maxME  = (ELG > E) ? ELG : E;
  u16* egpB   = (u16*)alloc((size_t)maxME * DD * 2);    // 128 MB, shared L1/L2
  u16* sgN    = (u16*)alloc((size_t)N * DD * 2);
  u16* dgduN  = (u16*)alloc((size_t)N * 2 * DD * 2);
  u16* suN    = (u16*)alloc((size_t)N * DD * 2);
  int* cnt_e  = (int*)alloc((size_t)E * 4);
  int* rptr_e = (int*)alloc((size_t)(E + 1) * 4);
  int* head_e = (int*)alloc((size_t)E * 4);
  int* eids_e = (int*)alloc((size_t)ELG * 4);
  int* srcs_e = (int*)alloc((size_t)ELG * 4);
  int* cnt_n  = (int*)alloc((size_t)N * 4);
  int* rptr_n = (int*)alloc((size_t)(N + 1) * 4);
  int* head_n = (int*)alloc((size_t)N * 4);
  int* eids_n = (int*)alloc((size_t)E * 4);
  int* srcs_n = (int*)alloc((size_t)E * 4);
  int* bsum   = (int*)alloc(512 * 4);
  if (ws_size < off) return;  // visible failure if ws too small

  float* xn_out = (float*)d_out;
  float* ea_out = (float*)d_out + (size_t)N * DD;

  // --- prep: weights + folded biases ---
  // wt slots 0..9 = eu{sg,dg,eg,du,su}, nu{sg,dg,eg,du,su}
  prep_weights<<<10, 256, 0, stream>>>(
      (const float*)d_in[5], (const float*)d_in[7], (const float*)d_in[9],
      (const float*)d_in[13], (const float*)d_in[11],
      (const float*)d_in[17], (const float*)d_in[19], (const float*)d_in[21],
      (const float*)d_in[25], (const float*)d_in[23], wt);
  fold_bias<<<1, 128, 0, stream>>>(
      (const float*)d_in[6], (const float*)d_in[8], (const float*)d_in[10],
      (const float*)d_in[14], (const float*)d_in[12],
      (const float*)d_in[18], (const float*)d_in[20], (const float*)d_in[22],
      (const float*)d_in[26], (const float*)d_in[24], biasF);

  // --- CSR builds: counts -> rowptr -> (eid, src) counting-sort ---
  hipMemsetAsync(cnt_e, 0, (size_t)E * 4, stream);
  hipMemsetAsync(cnt_n, 0, (size_t)N * 4, stream);
  hist_kernel<<<(ELG + 255) / 256, 256, 0, stream>>>(lgei + ELG, ELG, cnt_e);
  hist_kernel<<<(E + 255) / 256, 256, 0, stream>>>(gei + E, E, cnt_n);

  int NBe = (E + 1023) / 1024;
  scan1_kernel<<<NBe, 256, 0, stream>>>(cnt_e, E, rptr_e, bsum);
  scan2_kernel<<<1, 256, 0, stream>>>(bsum, NBe);
  scan3_kernel<<<(E + 255) / 256, 256, 0, stream>>>(rptr_e, bsum, E, ELG, head_e);
  eid_kernel<<<(ELG + 255) / 256, 256, 0, stream>>>(lgei, lgei + ELG, ELG, head_e,
                                                    eids_e, srcs_e);

  int NBn = (N + 1023) / 1024;
  scan1_kernel<<<NBn, 256, 0, stream>>>(cnt_n, N, rptr_n, bsum);
  scan2_kernel<<<1, 256, 0, stream>>>(bsum, NBn);
  scan3_kernel<<<(N + 255) / 256, 256, 0, stream>>>(rptr_n, bsum, N, E, head_n);
  eid_kernel<<<(E + 255) / 256, 256, 0, stream>>>(gei, gei + E, E, head_n,
                                                  eids_n, srcs_n);

  // --- Layer 1 (line graph; rows = g's edges) ---
  proj_kernel<true><<<(E + 127) / 128, 256, 0, stream>>>(
      E, ex, wt, biasF, sgE, dgduE, suE);
  proj_kernel<false><<<(ELG + 127) / 128, 256, 0, stream>>>(
      ELG, lga, wt + 2 * 16384, nullptr, egpB, nullptr, nullptr);
  gfin_kernel<<<(E + 15) / 16, 256, 0, stream>>>(
      E, rptr_e, eids_e, srcs_e, sgE, dgduE, suE, egpB,
      (const float*)d_in[15], (const float*)d_in[16], ex, ea_out);

  // --- Layer 2 (bond graph; attr = ea from d_out, f32 stream) ---
  proj_kernel<true><<<(N + 127) / 128, 256, 0, stream>>>(
      N, x, wt + 5 * 16384, biasF + 384, sgN, dgduN, suN);
  proj_kernel<false><<<(E + 127) / 128, 256, 0, stream>>>(
      E, ea_out, wt + 7 * 16384, nullptr, egpB, nullptr, nullptr);
  gfin_kernel<<<(N + 15) / 16, 256, 0, stream>>>(
      N, rptr_n, eids_n, srcs_n, sgN, dgduN, suN, egpB,
      (const float*)d_in[27], (const float*)d_in[28], x, xn_out);
}

// Round 5
// 950.635 us; speedup vs baseline: 1.3504x; 1.0128x over previous
//
#include <hip/hip_runtime.h>
#include <stdint.h>

#define DD 128

typedef __bf16 bf16x8 __attribute__((ext_vector_type(8)));
typedef float f32x4 __attribute__((ext_vector_type(4)));
typedef unsigned short u16;
typedef u16 u16x8 __attribute__((ext_vector_type(8)));

// Plain cast -> single HW cvt instruction (RNE), vs ~5 VALU ops manual.
__device__ __forceinline__ u16 f2bf(float f) {
  union { __bf16 h; u16 u; } v; v.h = (__bf16)f; return v.u;
}
__device__ __forceinline__ float bf2f(u16 b) {
  union { uint32_t u; float f; } v; v.u = (uint32_t)b << 16; return v.f;
}
__device__ __forceinline__ float silu_f(float x) {
  return x / (1.0f + __expf(-x));
}
__device__ __forceinline__ uint32_t pkbf(float lo, float hi) {
  return (uint32_t)f2bf(lo) | ((uint32_t)f2bf(hi) << 16);
}

// ---- f32 A staging (streamed): issue to regs / bf16-convert into LDS ----
// LDS layout: Ab[row*128 + ((cc ^ (row&7))<<3) + (k&7)]  (cc = k>>3).
// nt LOADS are fine (input is a pure stream, FETCH stayed at the clean
// 131 MB). nt STORES are NOT: they inflated WRITE 500->740 MB (no L2
// write-combining of 4B dwords) and evicted outputs the gfin gathers
// re-read -- reverted in store_acc.
struct ARegs { f32x4 v[8][2]; };

__device__ __forceinline__ void issue_A(ARegs& r, const float* __restrict__ src,
                                        int base, int M, int tid) {
#pragma unroll
  for (int i = 0; i < 8; ++i) {
    int id = tid + (i << 8);
    int row = id >> 4;
    int cc = id & 15;
    if (base + row < M) {
      const f32x4* p = (const f32x4*)(src + (size_t)(base + row) * DD + cc * 8);
      r.v[i][0] = __builtin_nontemporal_load(p);       // streamed, never reused
      r.v[i][1] = __builtin_nontemporal_load(p + 1);
    } else {
      r.v[i][0] = (f32x4){0.f, 0.f, 0.f, 0.f};
      r.v[i][1] = (f32x4){0.f, 0.f, 0.f, 0.f};
    }
  }
}

__device__ __forceinline__ void write_A(u16* Ab, const ARegs& r, int tid) {
#pragma unroll
  for (int i = 0; i < 8; ++i) {
    int id = tid + (i << 8);
    int row = id >> 4;
    int cc = id & 15;
    u16x8 o;
    o[0] = f2bf(r.v[i][0][0]); o[1] = f2bf(r.v[i][0][1]);
    o[2] = f2bf(r.v[i][0][2]); o[3] = f2bf(r.v[i][0][3]);
    o[4] = f2bf(r.v[i][1][0]); o[5] = f2bf(r.v[i][1][1]);
    o[6] = f2bf(r.v[i][1][2]); o[7] = f2bf(r.v[i][1][3]);
    *(u16x8*)&Ab[row * DD + ((cc ^ (row & 7)) << 3)] = o;
  }
}

// ---- B fragments preloaded to registers (64 VGPR per set). Loading the NEXT
// stage's set BEFORE the current stage's stores keeps stores in flight across
// the vmcnt wait (FIFO semantics: the B loads are older than the stores, so
// waiting for them leaves the stores outstanding). This was the stage-to-stage
// serializer: previously B loads followed 32 stores, so every B wait drained
// the whole store burst to L2. (R4 evidence: effective BW 1.88 -> 2.8 TB/s.)
struct BRegs { bf16x8 b[4][4]; };  // [kk][n]

__device__ __forceinline__ void load_B(BRegs& br, const u16* __restrict__ wt,
                                       int lane, int wc) {
  int g = lane >> 4, r15 = lane & 15;
  const u16* wbase = wt + (size_t)(wc * 64 + r15) * DD;
#pragma unroll
  for (int kk = 0; kk < 4; ++kk) {
    int ko = ((kk << 2) | g) << 3;
#pragma unroll
    for (int n = 0; n < 4; ++n)
      br.b[kk][n] = *(const bf16x8*)&wbase[n * 16 * DD + ko];
  }
}

// ---- MFMA stage from LDS A + register B. Same lane->k bijection on A and B
// so any hw k-permutation cancels.
__device__ __forceinline__ void mma_stage(const u16* Ab, const BRegs& br,
                                          f32x4 acc[4][4], int lane, int wr) {
  int g = lane >> 4, r15 = lane & 15, s = r15 & 7;
#pragma unroll
  for (int kk = 0; kk < 4; ++kk) {
    bf16x8 af[4];
#pragma unroll
    for (int m = 0; m < 4; ++m) {
      int rr = wr * 64 + m * 16 + r15;
      af[m] = *(const bf16x8*)&Ab[rr * DD + ((((kk << 2) | g) ^ s) << 3)];
    }
#pragma unroll
    for (int m = 0; m < 4; ++m)
#pragma unroll
      for (int n = 0; n < 4; ++n)
        acc[m][n] = __builtin_amdgcn_mfma_f32_16x16x32_bf16(af[m], br.b[kk][n], acc[m][n], 0, 0, 0);
  }
}

// acc init with per-column bias folded in (C-in of first MFMA). col = wc*64+n*16+l15,
// identical for all 4 j-rows of a reg -> one splat per n. bias==null -> zeros.
__device__ __forceinline__ void init_acc(f32x4 a[4][4], const float* __restrict__ bias,
                                         int lane, int wc) {
  int l15 = lane & 15;
#pragma unroll
  for (int n = 0; n < 4; ++n) {
    float b = bias ? bias[wc * 64 + n * 16 + l15] : 0.f;
    f32x4 v = {b, b, b, b};
#pragma unroll
    for (int m = 0; m < 4; ++m) a[m][n] = v;
  }
}

// C/D: col=lane&15, row=(lane>>4)*4+reg. shfl-pair -> u32 per 2 cols; store
// to out[row*rs + co + col]. PLAIN stores: L2 write-allocate merges the 4B
// dwords into full lines (exact 500 MB) and keeps them hot for gfin.
__device__ __forceinline__ void store_acc(const f32x4 acc[4][4], u16* __restrict__ out,
                                          size_t rs, int co, int base, int M,
                                          int lane, int wr, int wc) {
  int l15 = lane & 15;
  bool oddl = lane & 1;
#pragma unroll
  for (int m = 0; m < 4; ++m) {
    int rb = wr * 64 + m * 16 + ((lane >> 4) << 2);
#pragma unroll
    for (int j = 0; j < 4; ++j) {
      int row = rb + j;
      bool act = (base + row < M);
      size_t rowoff = (size_t)(base + row) * rs + co;
#pragma unroll
      for (int n0 = 0; n0 < 4; n0 += 2) {
        int c0 = wc * 64 + n0 * 16 + l15;
        float v0 = acc[m][n0][j];
        float v1 = acc[m][n0 + 1][j];
        float t0 = __shfl_xor(v0, 1);
        float t1 = __shfl_xor(v1, 1);
        uint32_t pk = oddl ? pkbf(t1, v1) : pkbf(v0, t0);
        int col2 = oddl ? (c0 + 15) : c0;
        if (act) *(uint32_t*)&out[rowoff + col2] = pk;
      }
    }
  }
}

// ================= projection GEMMs (pure streaming, no gathers/atomics) ====
// One 128-row tile per block, 256 threads, 64x64 wave tile, (256,2) -- the
// round-0 shape (cleanest HBM traffic). B-prefetch-to-regs breaks the
// stage-to-stage vmcnt interlock; nt loads for the input stream only.
template <bool FOUR>
__global__ void __launch_bounds__(256, 2) proj_kernel(
    int M, const float* __restrict__ src, const u16* __restrict__ wt,
    const float* __restrict__ bF,  // folded biases [3][128]: sg+dg+eg, du, su
    u16* __restrict__ o_sg, u16* __restrict__ o_dgdu, u16* __restrict__ o_su) {
  __shared__ u16 Ab[128 * DD];  // 32 KB
  int tid = threadIdx.x, lane = tid & 63, wid = tid >> 6;
  int wr = wid >> 1, wc = wid & 1;
  int base = blockIdx.x * 128;
  BRegs b0, b1;
  {
    ARegs ar;
    issue_A(ar, src, base, M, tid);   // HBM loads first (longest pole)
    load_B(b0, wt + 0 * 16384, lane, wc);  // L2 loads behind them
    write_A(Ab, ar, tid);             // waits A only (B newer in FIFO)
  }
  __syncthreads();
  f32x4 acc[4][4];
  init_acc(acc, FOUR ? bF : nullptr, lane, wc);
  mma_stage(Ab, b0, acc, lane, wr);                        // sg (or egp)
  if (FOUR) {
    load_B(b1, wt + 1 * 16384, lane, wc);    // before stores: stores stay in flight
    store_acc(acc, o_sg, DD, 0, base, M, lane, wr, wc);
    init_acc(acc, nullptr, lane, wc);
    mma_stage(Ab, b1, acc, lane, wr);                      // dg (bias in sg)
    load_B(b0, wt + 3 * 16384, lane, wc);
    store_acc(acc, o_dgdu, 2 * DD, 0, base, M, lane, wr, wc);
    init_acc(acc, bF + 128, lane, wc);
    mma_stage(Ab, b0, acc, lane, wr);                      // du + bdu
    load_B(b1, wt + 4 * 16384, lane, wc);
    store_acc(acc, o_dgdu, 2 * DD, DD, base, M, lane, wr, wc);
    init_acc(acc, bF + 256, lane, wc);
    mma_stage(Ab, b1, acc, lane, wr);                      // su + bsu
    store_acc(acc, o_su, DD, 0, base, M, lane, wr, wc);
  } else {
    store_acc(acc, o_sg, DD, 0, base, M, lane, wr, wc);
  }
}

// ================= CSR build =================
__global__ void __launch_bounds__(256) hist_kernel(const int* __restrict__ dst,
                                                   int Me, int* __restrict__ cnt) {
  int i = blockIdx.x * blockDim.x + threadIdx.x;
  if (i < Me) atomicAdd(&cnt[dst[i]], 1);
}

__global__ void __launch_bounds__(256) scan1_kernel(const int* __restrict__ cnt, int M,
                                                    int* __restrict__ out,
                                                    int* __restrict__ bsum) {
  __shared__ int sh[256];
  int t = threadIdx.x;
  int i0 = blockIdx.x * 1024 + t * 4;
  int v[4];
#pragma unroll
  for (int k = 0; k < 4; ++k) v[k] = (i0 + k < M) ? cnt[i0 + k] : 0;
  int s = v[0] + v[1] + v[2] + v[3];
  sh[t] = s;
  __syncthreads();
#pragma unroll
  for (int off = 1; off < 256; off <<= 1) {
    int x = (t >= off) ? sh[t - off] : 0;
    __syncthreads();
    sh[t] += x;
    __syncthreads();
  }
  int run = sh[t] - s;  // exclusive
  if (t == 255) bsum[blockIdx.x] = sh[255];
#pragma unroll
  for (int k = 0; k < 4; ++k) {
    if (i0 + k < M) out[i0 + k] = run;
    run += v[k];
  }
}

__global__ void __launch_bounds__(256) scan2_kernel(int* __restrict__ bsum, int NB) {
  __shared__ int sh[512];
  int t = threadIdx.x;
  for (int i = t; i < 512; i += 256) sh[i] = (i < NB) ? bsum[i] : 0;
  __syncthreads();
  for (int off = 1; off < 512; off <<= 1) {
    int tmp[2];
#pragma unroll
    for (int q = 0; q < 2; ++q) {
      int i = t + q * 256;
      tmp[q] = (i >= off) ? sh[i - off] : 0;
    }
    __syncthreads();
#pragma unroll
    for (int q = 0; q < 2; ++q) sh[t + q * 256] += tmp[q];
    __syncthreads();
  }
  for (int i = t; i < NB; i += 256) bsum[i] = (i == 0) ? 0 : sh[i - 1];
}

__global__ void __launch_bounds__(256) scan3_kernel(int* __restrict__ rowptr,
                                                    const int* __restrict__ bscan,
                                                    int M, int Medges,
                                                    int* __restrict__ head) {
  int i = blockIdx.x * blockDim.x + threadIdx.x;
  if (i < M) {
    int v = rowptr[i] + bscan[i >> 10];
    rowptr[i] = v;
    head[i] = v;
  }
  if (i == 0) rowptr[M] = Medges;
}

// Counting-sort: slot s gets edge id + its src (4B scatters on L2-resident arrays).
__global__ void __launch_bounds__(256) eid_kernel(const int* __restrict__ src,
                                                  const int* __restrict__ dst, int Me,
                                                  int* __restrict__ head,
                                                  int* __restrict__ eids,
                                                  int* __restrict__ srcs) {
  int i = blockIdx.x * blockDim.x + threadIdx.x;
  if (i < Me) {
    int s = atomicAdd(&head[dst[i]], 1);
    eids[s] = i;
    srcs[s] = src[i];
  }
}

// ================= misc prep =================
// W (k-major [128][128] f32) -> wt[n*128+k] bf16.
__global__ void prep_weights(const float* __restrict__ w0, const float* __restrict__ w1,
                             const float* __restrict__ w2, const float* __restrict__ w3,
                             const float* __restrict__ w4, const float* __restrict__ w5,
                             const float* __restrict__ w6, const float* __restrict__ w7,
                             const float* __restrict__ w8, const float* __restrict__ w9,
                             u16* __restrict__ wt) {
  const float* W;
  switch (blockIdx.x) {
    case 0: W = w0; break; case 1: W = w1; break; case 2: W = w2; break;
    case 3: W = w3; break; case 4: W = w4; break; case 5: W = w5; break;
    case 6: W = w6; break; case 7: W = w7; break; case 8: W = w8; break;
    default: W = w9; break;
  }
  u16* dst = wt + blockIdx.x * 16384;
  for (int o = threadIdx.x; o < 16384; o += 256) {
    int n = o >> 7, k = o & 127;
    dst[o] = f2bf(W[k * DD + n]);
  }
}

// Folded bias table: [0..2]*128 = eu {sg+dg+eg, du, su}; [3..5]*128 = nu same.
__global__ void fold_bias(const float* __restrict__ e_sg, const float* __restrict__ e_dg,
                          const float* __restrict__ e_eg, const float* __restrict__ e_du,
                          const float* __restrict__ e_su,
                          const float* __restrict__ n_sg, const float* __restrict__ n_dg,
                          const float* __restrict__ n_eg, const float* __restrict__ n_du,
                          const float* __restrict__ n_su, float* __restrict__ out) {
  int i = threadIdx.x;
  if (i < 128) {
    out[i]        = e_sg[i] + e_dg[i] + e_eg[i];
    out[128 + i]  = e_du[i];
    out[256 + i]  = e_su[i];
    out[384 + i]  = n_sg[i] + n_dg[i] + n_eg[i];
    out[512 + i]  = n_du[i];
    out[640 + i]  = n_su[i];
  }
}

// ============ gather-finalize: 16 lanes/row, 8 cols/lane, 4 rows/wave ========
// per row r: for s in [rptr[r],rptr[r+1]):
//   e=eids[s], sv=srcs[s]
//   gate = silu(sg'[r] + dg[sv] + egp[e]); ax += gate * du'[sv]
// vx = su'[r] + ax; LN; silu; + resid(f32); write f32 out.
// (biases pre-folded: sg' = sg+bsg+bdg+beg, du' = du+bdu, su' = su+bsu)
__global__ void __launch_bounds__(256) gfin_kernel(
    int M, const int* __restrict__ rptr, const int* __restrict__ eids,
    const int* __restrict__ srcs,
    const u16* __restrict__ sg_t, const u16* __restrict__ dgdu_t,
    const u16* __restrict__ su_t, const u16* __restrict__ egp,
    const float* __restrict__ gamma, const float* __restrict__ beta,
    const float* __restrict__ resid, float* __restrict__ out) {
  int gtid = blockIdx.x * blockDim.x + threadIdx.x;
  int r = gtid >> 4;
  int l16 = gtid & 15;
  if (r >= M) return;
  int c = l16 * 8;

  u16x8 sgp = *(const u16x8*)&sg_t[(size_t)r * DD + c];
  float sg[8], ax[8];
#pragma unroll
  for (int k = 0; k < 8; ++k) { sg[k] = bf2f(sgp[k]); ax[k] = 0.f; }

  int segb = rptr[r], sege = rptr[r + 1];
  for (int s = segb; s < sege; ++s) {
    int e = eids[s];
    int sv = srcs[s];
    u16x8 gp = *(const u16x8*)&egp[(size_t)e * DD + c];
    u16x8 dgp = *(const u16x8*)&dgdu_t[(size_t)sv * (2 * DD) + c];
    u16x8 dup = *(const u16x8*)&dgdu_t[(size_t)sv * (2 * DD) + DD + c];
#pragma unroll
    for (int k = 0; k < 8; ++k) {
      float g = silu_f(sg[k] + bf2f(dgp[k]) + bf2f(gp[k]));
      ax[k] += g * bf2f(dup[k]);
    }
  }

  u16x8 sup = *(const u16x8*)&su_t[(size_t)r * DD + c];
  float v[8];
  float sum = 0.f;
#pragma unroll
  for (int k = 0; k < 8; ++k) { v[k] = bf2f(sup[k]) + ax[k]; sum += v[k]; }
#pragma unroll
  for (int off = 1; off <= 8; off <<= 1) sum += __shfl_xor(sum, off);
  float mean = sum * (1.0f / 128.0f);
  float sq = 0.f;
#pragma unroll
  for (int k = 0; k < 8; ++k) { v[k] -= mean; sq += v[k] * v[k]; }
#pragma unroll
  for (int off = 1; off <= 8; off <<= 1) sq += __shfl_xor(sq, off);
  float rs = rsqrtf(sq * (1.0f / 128.0f) + 1e-5f);

  float4 gm0 = *(const float4*)&gamma[c];
  float4 gm1 = *(const float4*)&gamma[c + 4];
  float4 bt0 = *(const float4*)&beta[c];
  float4 bt1 = *(const float4*)&beta[c + 4];
  float4 rr0 = *(const float4*)&resid[(size_t)r * DD + c];
  float4 rr1 = *(const float4*)&resid[(size_t)r * DD + c + 4];
  float gmv[8] = {gm0.x, gm0.y, gm0.z, gm0.w, gm1.x, gm1.y, gm1.z, gm1.w};
  float btv[8] = {bt0.x, bt0.y, bt0.z, bt0.w, bt1.x, bt1.y, bt1.z, bt1.w};
  float rrv[8] = {rr0.x, rr0.y, rr0.z, rr0.w, rr1.x, rr1.y, rr1.z, rr1.w};
  float o[8];
#pragma unroll
  for (int k = 0; k < 8; ++k)
    o[k] = silu_f(v[k] * rs * gmv[k] + btv[k]) + rrv[k];
  float4 o0 = {o[0], o[1], o[2], o[3]};
  float4 o1 = {o[4], o[5], o[6], o[7]};
  *(float4*)&out[(size_t)r * DD + c] = o0;
  *(float4*)&out[(size_t)r * DD + c + 4] = o1;
}

extern "C" void kernel_launch(void* const* d_in, const int* in_sizes, int n_in,
                              void* d_out, int out_size, void* d_ws, size_t ws_size,
                              hipStream_t stream) {
  const float* x   = (const float*)d_in[0];
  const float* ex  = (const float*)d_in[1];
  const float* lga = (const float*)d_in[2];
  const int* gei   = (const int*)d_in[3];
  const int* lgei  = (const int*)d_in[4];
  int N   = in_sizes[0] / DD;
  int E   = in_sizes[3] / 2;
  int ELG = in_sizes[4] / 2;

  char* p = (char*)d_ws;
  size_t off = 0;
  auto alloc = [&](size_t bytes) { char* q = p + off; off += (bytes + 255) & ~255ull; return q; };

  u16* wt     = (u16*)alloc((size_t)10 * 16384 * 2);
  float* biasF = (float*)alloc(768 * 4);
  u16* sgE    = (u16*)alloc((size_t)E * DD * 2);        // 128 MB
  u16* dgduE  = (u16*)alloc((size_t)E * 2 * DD * 2);    // 256 MB
  u16* suE    = (u16*)alloc((size_t)E * DD * 2);        // 128 MB
  int  maxME  = (ELG > E) ? ELG : E;
  u16* egpB   = (u16*)alloc((size_t)maxME * DD * 2);    // 128 MB, shared L1/L2
  u16* sgN    = (u16*)alloc((size_t)N * DD * 2);
  u16* dgduN  = (u16*)alloc((size_t)N * 2 * DD * 2);
  u16* suN    = (u16*)alloc((size_t)N * DD * 2);
  int* cnt_e  = (int*)alloc((size_t)E * 4);
  int* rptr_e = (int*)alloc((size_t)(E + 1) * 4);
  int* head_e = (int*)alloc((size_t)E * 4);
  int* eids_e = (int*)alloc((size_t)ELG * 4);
  int* srcs_e = (int*)alloc((size_t)ELG * 4);
  int* cnt_n  = (int*)alloc((size_t)N * 4);
  int* rptr_n = (int*)alloc((size_t)(N + 1) * 4);
  int* head_n = (int*)alloc((size_t)N * 4);
  int* eids_n = (int*)alloc((size_t)E * 4);
  int* srcs_n = (int*)alloc((size_t)E * 4);
  int* bsum   = (int*)alloc(512 * 4);
  if (ws_size < off) return;  // visible failure if ws too small

  float* xn_out = (float*)d_out;
  float* ea_out = (float*)d_out + (size_t)N * DD;

  // --- prep: weights + folded biases ---
  // wt slots 0..9 = eu{sg,dg,eg,du,su}, nu{sg,dg,eg,du,su}
  prep_weights<<<10, 256, 0, stream>>>(
      (const float*)d_in[5], (const float*)d_in[7], (const float*)d_in[9],
      (const float*)d_in[13], (const float*)d_in[11],
      (const float*)d_in[17], (const float*)d_in[19], (const float*)d_in[21],
      (const float*)d_in[25], (const float*)d_in[23], wt);
  fold_bias<<<1, 128, 0, stream>>>(
      (const float*)d_in[6], (const float*)d_in[8], (const float*)d_in[10],
      (const float*)d_in[14], (const float*)d_in[12],
      (const float*)d_in[18], (const float*)d_in[20], (const float*)d_in[22],
      (const float*)d_in[26], (const float*)d_in[24], biasF);

  // --- CSR builds: counts -> rowptr -> (eid, src) counting-sort ---
  hipMemsetAsync(cnt_e, 0, (size_t)E * 4, stream);
  hipMemsetAsync(cnt_n, 0, (size_t)N * 4, stream);
  hist_kernel<<<(ELG + 255) / 256, 256, 0, stream>>>(lgei + ELG, ELG, cnt_e);
  hist_kernel<<<(E + 255) / 256, 256, 0, stream>>>(gei + E, E, cnt_n);

  int NBe = (E + 1023) / 1024;
  scan1_kernel<<<NBe, 256, 0, stream>>>(cnt_e, E, rptr_e, bsum);
  scan2_kernel<<<1, 256, 0, stream>>>(bsum, NBe);
  scan3_kernel<<<(E + 255) / 256, 256, 0, stream>>>(rptr_e, bsum, E, ELG, head_e);
  eid_kernel<<<(ELG + 255) / 256, 256, 0, stream>>>(lgei, lgei + ELG, ELG, head_e,
                                                    eids_e, srcs_e);

  int NBn = (N + 1023) / 1024;
  scan1_kernel<<<NBn, 256, 0, stream>>>(cnt_n, N, rptr_n, bsum);
  scan2_kernel<<<1, 256, 0, stream>>>(bsum, NBn);
  scan3_kernel<<<(N + 255) / 256, 256, 0, stream>>>(rptr_n, bsum, N, E, head_n);
  eid_kernel<<<(E + 255) / 256, 256, 0, stream>>>(gei, gei + E, E, head_n,
                                                  eids_n, srcs_n);

  // --- Layer 1 (line graph; rows = g's edges) ---
  proj_kernel<true><<<(E + 127) / 128, 256, 0, stream>>>(
      E, ex, wt, biasF, sgE, dgduE, suE);
  proj_kernel<false><<<(ELG + 127) / 128, 256, 0, stream>>>(
      ELG, lga, wt + 2 * 16384, nullptr, egpB, nullptr, nullptr);
  gfin_kernel<<<(E + 15) / 16, 256, 0, stream>>>(
      E, rptr_e, eids_e, srcs_e, sgE, dgduE, suE, egpB,
      (const float*)d_in[15], (const float*)d_in[16], ex, ea_out);

  // --- Layer 2 (bond graph; attr = ea from d_out, f32 stream) ---
  proj_kernel<true><<<(N + 127) / 128, 256, 0, stream>>>(
      N, x, wt + 5 * 16384, biasF + 384, sgN, dgduN, suN);
  proj_kernel<false><<<(E + 127) / 128, 256, 0, stream>>>(
      E, ea_out, wt + 7 * 16384, nullptr, egpB, nullptr, nullptr);
  gfin_kernel<<<(N + 15) / 16, 256, 0, stream>>>(
      N, rptr_n, eids_n, srcs_n, sgN, dgduN, suN, egpB,
      (const float*)d_in[27], (const float*)d_in[28], x, xn_out);
}

// Round 6
// 916.399 us; speedup vs baseline: 1.4008x; 1.0374x over previous
//
#include <hip/hip_runtime.h>
#include <stdint.h>

#define DD 128

typedef __bf16 bf16x8 __attribute__((ext_vector_type(8)));
typedef float f32x4 __attribute__((ext_vector_type(4)));
typedef unsigned short u16;
typedef u16 u16x8 __attribute__((ext_vector_type(8)));

// Plain cast -> single HW cvt instruction (RNE), vs ~5 VALU ops manual.
__device__ __forceinline__ u16 f2bf(float f) {
  union { __bf16 h; u16 u; } v; v.h = (__bf16)f; return v.u;
}
__device__ __forceinline__ float bf2f(u16 b) {
  union { uint32_t u; float f; } v; v.u = (uint32_t)b << 16; return v.f;
}
__device__ __forceinline__ float silu_f(float x) {
  return x / (1.0f + __expf(-x));
}
__device__ __forceinline__ uint32_t pkbf(float lo, float hi) {
  return (uint32_t)f2bf(lo) | ((uint32_t)f2bf(hi) << 16);
}

// ---- f32 A staging (streamed): issue to regs / bf16-convert into LDS ----
// LDS layout: Ab[row*128 + ((cc ^ (row&7))<<3) + (k&7)]  (cc = k>>3).
// PLAIN loads only. nt-load experiments (R4/R5): inputs ex/x are RE-READ by
// gfin as the residual; nt skips L2/L3 allocation -> gfin lost its cache
// hits and proj traffic inflated (FETCH 129->182, WRITE 500->578). Reverted.
struct ARegs { f32x4 v[8][2]; };

__device__ __forceinline__ void issue_A(ARegs& r, const float* __restrict__ src,
                                        int base, int M, int tid) {
#pragma unroll
  for (int i = 0; i < 8; ++i) {
    int id = tid + (i << 8);
    int row = id >> 4;
    int cc = id & 15;
    if (base + row < M) {
      const f32x4* p = (const f32x4*)(src + (size_t)(base + row) * DD + cc * 8);
      r.v[i][0] = p[0];
      r.v[i][1] = p[1];
    } else {
      r.v[i][0] = (f32x4){0.f, 0.f, 0.f, 0.f};
      r.v[i][1] = (f32x4){0.f, 0.f, 0.f, 0.f};
    }
  }
}

__device__ __forceinline__ void write_A(u16* Ab, const ARegs& r, int tid) {
#pragma unroll
  for (int i = 0; i < 8; ++i) {
    int id = tid + (i << 8);
    int row = id >> 4;
    int cc = id & 15;
    u16x8 o;
    o[0] = f2bf(r.v[i][0][0]); o[1] = f2bf(r.v[i][0][1]);
    o[2] = f2bf(r.v[i][0][2]); o[3] = f2bf(r.v[i][0][3]);
    o[4] = f2bf(r.v[i][1][0]); o[5] = f2bf(r.v[i][1][1]);
    o[6] = f2bf(r.v[i][1][2]); o[7] = f2bf(r.v[i][1][3]);
    *(u16x8*)&Ab[row * DD + ((cc ^ (row & 7)) << 3)] = o;
  }
}

// ---- B fragments preloaded to registers (16 VGPR per set). Loading the NEXT
// stage's set BEFORE the current stage's stores keeps stores in flight across
// the vmcnt wait (FIFO semantics: B loads older than the stores, so waiting
// for B leaves the stores outstanding). R4/R5 evidence: effective BW
// 1.88 -> 2.5+ TB/s on the proj<true> dispatch.
struct BRegs { bf16x8 b[4][4]; };  // [kk][n]

__device__ __forceinline__ void load_B(BRegs& br, const u16* __restrict__ wt,
                                       int lane, int wc) {
  int g = lane >> 4, r15 = lane & 15;
  const u16* wbase = wt + (size_t)(wc * 64 + r15) * DD;
#pragma unroll
  for (int kk = 0; kk < 4; ++kk) {
    int ko = ((kk << 2) | g) << 3;
#pragma unroll
    for (int n = 0; n < 4; ++n)
      br.b[kk][n] = *(const bf16x8*)&wbase[n * 16 * DD + ko];
  }
}

// ---- MFMA stage from LDS A + register B. Same lane->k bijection on A and B
// so any hw k-permutation cancels.
__device__ __forceinline__ void mma_stage(const u16* Ab, const BRegs& br,
                                          f32x4 acc[4][4], int lane, int wr) {
  int g = lane >> 4, r15 = lane & 15, s = r15 & 7;
#pragma unroll
  for (int kk = 0; kk < 4; ++kk) {
    bf16x8 af[4];
#pragma unroll
    for (int m = 0; m < 4; ++m) {
      int rr = wr * 64 + m * 16 + r15;
      af[m] = *(const bf16x8*)&Ab[rr * DD + ((((kk << 2) | g) ^ s) << 3)];
    }
#pragma unroll
    for (int m = 0; m < 4; ++m)
#pragma unroll
      for (int n = 0; n < 4; ++n)
        acc[m][n] = __builtin_amdgcn_mfma_f32_16x16x32_bf16(af[m], br.b[kk][n], acc[m][n], 0, 0, 0);
  }
}

// acc init with per-column bias folded in (C-in of first MFMA). col = wc*64+n*16+l15,
// identical for all 4 j-rows of a reg -> one splat per n. bias==null -> zeros.
__device__ __forceinline__ void init_acc(f32x4 a[4][4], const float* __restrict__ bias,
                                         int lane, int wc) {
  int l15 = lane & 15;
#pragma unroll
  for (int n = 0; n < 4; ++n) {
    float b = bias ? bias[wc * 64 + n * 16 + l15] : 0.f;
    f32x4 v = {b, b, b, b};
#pragma unroll
    for (int m = 0; m < 4; ++m) a[m][n] = v;
  }
}

// C/D: col=lane&15, row=(lane>>4)*4+reg. shfl-pair -> u32 per 2 cols; store
// to out[orow*rs + co + col]. PLAIN stores (L2 write-allocate merges lines,
// keeps outputs hot for gfin; nt stores inflated WRITE 500->740, R4).
// Optional sPerm (LDS): output row permutation (egp written in gather order
// so gfin reads it sequentially).
__device__ __forceinline__ void store_acc(const f32x4 acc[4][4], u16* __restrict__ out,
                                          size_t rs, int co, int base, int M,
                                          int lane, int wr, int wc,
                                          const int* sPerm) {
  int l15 = lane & 15;
  bool oddl = lane & 1;
#pragma unroll
  for (int m = 0; m < 4; ++m) {
    int rb = wr * 64 + m * 16 + ((lane >> 4) << 2);
#pragma unroll
    for (int j = 0; j < 4; ++j) {
      int row = rb + j;
      bool act = (base + row < M);
      int orow = sPerm ? (act ? sPerm[row] : 0) : (base + row);
      size_t rowoff = (size_t)orow * rs + co;
#pragma unroll
      for (int n0 = 0; n0 < 4; n0 += 2) {
        int c0 = wc * 64 + n0 * 16 + l15;
        float v0 = acc[m][n0][j];
        float v1 = acc[m][n0 + 1][j];
        float t0 = __shfl_xor(v0, 1);
        float t1 = __shfl_xor(v1, 1);
        uint32_t pk = oddl ? pkbf(t1, v1) : pkbf(v0, t0);
        int col2 = oddl ? (c0 + 15) : c0;
        if (act) *(uint32_t*)&out[rowoff + col2] = pk;
      }
    }
  }
}

// ================= projection GEMMs (pure streaming, no gathers/atomics) ====
// One 128-row tile per block, 256 threads, 64x64 wave tile, (256,2) -- the
// round-0 shape (cleanest HBM traffic: 129 fetch / 500 write MB). Persistent
// blocks (R1) and 512-thread blocks (R2) both inflated traffic and regressed.
// Kept: B-prefetch-to-regs (breaks stage-to-stage vmcnt interlock), bias in
// acc-init, optional write permutation for the egp path.
template <bool FOUR>
__global__ void __launch_bounds__(256, 2) proj_kernel(
    int M, const float* __restrict__ src, const u16* __restrict__ wt,
    const float* __restrict__ bF,  // folded biases [3][128]: sg+dg+eg, du, su
    const int* __restrict__ perm,  // optional output-row permutation
    u16* __restrict__ o_sg, u16* __restrict__ o_dgdu, u16* __restrict__ o_su) {
  __shared__ u16 Ab[128 * DD];  // 32 KB
  __shared__ int sPerm[128];
  int tid = threadIdx.x, lane = tid & 63, wid = tid >> 6;
  int wr = wid >> 1, wc = wid & 1;
  int base = blockIdx.x * 128;
  BRegs b0, b1;
  {
    ARegs ar;
    issue_A(ar, src, base, M, tid);        // HBM loads first (longest pole)
    if (perm && tid < 128)
      sPerm[tid] = (base + tid < M) ? perm[base + tid] : 0;
    load_B(b0, wt + 0 * 16384, lane, wc);  // L2 loads behind them
    write_A(Ab, ar, tid);                  // waits A only (B newer in FIFO)
  }
  __syncthreads();
  f32x4 acc[4][4];
  init_acc(acc, FOUR ? bF : nullptr, lane, wc);
  mma_stage(Ab, b0, acc, lane, wr);                        // sg (or egp)
  if (FOUR) {
    load_B(b1, wt + 1 * 16384, lane, wc);  // before stores: stores stay in flight
    store_acc(acc, o_sg, DD, 0, base, M, lane, wr, wc, nullptr);
    init_acc(acc, nullptr, lane, wc);
    mma_stage(Ab, b1, acc, lane, wr);                      // dg (bias in sg)
    load_B(b0, wt + 3 * 16384, lane, wc);
    store_acc(acc, o_dgdu, 2 * DD, 0, base, M, lane, wr, wc, nullptr);
    init_acc(acc, bF + 128, lane, wc);
    mma_stage(Ab, b0, acc, lane, wr);                      // du + bdu
    load_B(b1, wt + 4 * 16384, lane, wc);
    store_acc(acc, o_dgdu, 2 * DD, DD, base, M, lane, wr, wc, nullptr);
    init_acc(acc, bF + 256, lane, wc);
    mma_stage(Ab, b1, acc, lane, wr);                      // su + bsu
    store_acc(acc, o_su, DD, 0, base, M, lane, wr, wc, nullptr);
  } else {
    store_acc(acc, o_sg, DD, 0, base, M, lane, wr, wc, perm ? sPerm : nullptr);
  }
}

// ================= CSR build =================
__global__ void __launch_bounds__(256) hist_kernel(const int* __restrict__ dst,
                                                   int Me, int* __restrict__ cnt) {
  int i = blockIdx.x * blockDim.x + threadIdx.x;
  if (i < Me) atomicAdd(&cnt[dst[i]], 1);
}

__global__ void __launch_bounds__(256) scan1_kernel(const int* __restrict__ cnt, int M,
                                                    int* __restrict__ out,
                                                    int* __restrict__ bsum) {
  __shared__ int sh[256];
  int t = threadIdx.x;
  int i0 = blockIdx.x * 1024 + t * 4;
  int v[4];
#pragma unroll
  for (int k = 0; k < 4; ++k) v[k] = (i0 + k < M) ? cnt[i0 + k] : 0;
  int s = v[0] + v[1] + v[2] + v[3];
  sh[t] = s;
  __syncthreads();
#pragma unroll
  for (int off = 1; off < 256; off <<= 1) {
    int x = (t >= off) ? sh[t - off] : 0;
    __syncthreads();
    sh[t] += x;
    __syncthreads();
  }
  int run = sh[t] - s;  // exclusive
  if (t == 255) bsum[blockIdx.x] = sh[255];
#pragma unroll
  for (int k = 0; k < 4; ++k) {
    if (i0 + k < M) out[i0 + k] = run;
    run += v[k];
  }
}

__global__ void __launch_bounds__(256) scan2_kernel(int* __restrict__ bsum, int NB) {
  __shared__ int sh[512];
  int t = threadIdx.x;
  for (int i = t; i < 512; i += 256) sh[i] = (i < NB) ? bsum[i] : 0;
  __syncthreads();
  for (int off = 1; off < 512; off <<= 1) {
    int tmp[2];
#pragma unroll
    for (int q = 0; q < 2; ++q) {
      int i = t + q * 256;
      tmp[q] = (i >= off) ? sh[i - off] : 0;
    }
    __syncthreads();
#pragma unroll
    for (int q = 0; q < 2; ++q) sh[t + q * 256] += tmp[q];
    __syncthreads();
  }
  for (int i = t; i < NB; i += 256) bsum[i] = (i == 0) ? 0 : sh[i - 1];
}

__global__ void __launch_bounds__(256) scan3_kernel(int* __restrict__ rowptr,
                                                    const int* __restrict__ bscan,
                                                    int M, int Medges,
                                                    int* __restrict__ head) {
  int i = blockIdx.x * blockDim.x + threadIdx.x;
  if (i < M) {
    int v = rowptr[i] + bscan[i >> 10];
    rowptr[i] = v;
    head[i] = v;
  }
  if (i == 0) rowptr[M] = Medges;
}

// Counting-sort: slot s gets the edge's src; pos[e] = s records the inverse
// permutation so proj<false> can write egp directly in gather order.
__global__ void __launch_bounds__(256) eid_kernel(const int* __restrict__ src,
                                                  const int* __restrict__ dst, int Me,
                                                  int* __restrict__ head,
                                                  int* __restrict__ srcs,
                                                  int* __restrict__ pos) {
  int i = blockIdx.x * blockDim.x + threadIdx.x;
  if (i < Me) {
    int s = atomicAdd(&head[dst[i]], 1);
    srcs[s] = src[i];
    pos[i] = s;
  }
}

// ================= misc prep =================
// W (k-major [128][128] f32) -> wt[n*128+k] bf16.
__global__ void prep_weights(const float* __restrict__ w0, const float* __restrict__ w1,
                             const float* __restrict__ w2, const float* __restrict__ w3,
                             const float* __restrict__ w4, const float* __restrict__ w5,
                             const float* __restrict__ w6, const float* __restrict__ w7,
                             const float* __restrict__ w8, const float* __restrict__ w9,
                             u16* __restrict__ wt) {
  const float* W;
  switch (blockIdx.x) {
    case 0: W = w0; break; case 1: W = w1; break; case 2: W = w2; break;
    case 3: W = w3; break; case 4: W = w4; break; case 5: W = w5; break;
    case 6: W = w6; break; case 7: W = w7; break; case 8: W = w8; break;
    default: W = w9; break;
  }
  u16* dst = wt + blockIdx.x * 16384;
  for (int o = threadIdx.x; o < 16384; o += 256) {
    int n = o >> 7, k = o & 127;
    dst[o] = f2bf(W[k * DD + n]);
  }
}

// Folded bias table: [0..2]*128 = eu {sg+dg+eg, du, su}; [3..5]*128 = nu same.
__global__ void fold_bias(const float* __restrict__ e_sg, const float* __restrict__ e_dg,
                          const float* __restrict__ e_eg, const float* __restrict__ e_du,
                          const float* __restrict__ e_su,
                          const float* __restrict__ n_sg, const float* __restrict__ n_dg,
                          const float* __restrict__ n_eg, const float* __restrict__ n_du,
                          const float* __restrict__ n_su, float* __restrict__ out) {
  int i = threadIdx.x;
  if (i < 128) {
    out[i]        = e_sg[i] + e_dg[i] + e_eg[i];
    out[128 + i]  = e_du[i];
    out[256 + i]  = e_su[i];
    out[384 + i]  = n_sg[i] + n_dg[i] + n_eg[i];
    out[512 + i]  = n_du[i];
    out[640 + i]  = n_su[i];
  }
}

// ============ gather-finalize: 16 lanes/row, 8 cols/lane, 4 rows/wave ========
// per row r: for s in [rptr[r],rptr[r+1]):
//   sv=srcs[s]
//   gate = silu(sg'[r] + dg[sv] + egp[s]); ax += gate * du'[sv]
// egp is pre-permuted (written at pos[e]) -> sequential reads here, no eids.
// vx = su'[r] + ax; LN; silu; + resid(f32); write f32 out.
// (biases pre-folded: sg' = sg+bsg+bdg+beg, du' = du+bdu, su' = su+bsu)
__global__ void __launch_bounds__(256) gfin_kernel(
    int M, const int* __restrict__ rptr,
    const int* __restrict__ srcs,
    const u16* __restrict__ sg_t, const u16* __restrict__ dgdu_t,
    const u16* __restrict__ su_t, const u16* __restrict__ egp,
    const float* __restrict__ gamma, const float* __restrict__ beta,
    const float* __restrict__ resid, float* __restrict__ out) {
  int gtid = blockIdx.x * blockDim.x + threadIdx.x;
  int r = gtid >> 4;
  int l16 = gtid & 15;
  if (r >= M) return;
  int c = l16 * 8;

  u16x8 sgp = *(const u16x8*)&sg_t[(size_t)r * DD + c];
  float sg[8], ax[8];
#pragma unroll
  for (int k = 0; k < 8; ++k) { sg[k] = bf2f(sgp[k]); ax[k] = 0.f; }

  int segb = rptr[r], sege = rptr[r + 1];
  for (int s = segb; s < sege; ++s) {
    int sv = srcs[s];
    u16x8 gp = *(const u16x8*)&egp[(size_t)s * DD + c];
    u16x8 dgp = *(const u16x8*)&dgdu_t[(size_t)sv * (2 * DD) + c];
    u16x8 dup = *(const u16x8*)&dgdu_t[(size_t)sv * (2 * DD) + DD + c];
#pragma unroll
    for (int k = 0; k < 8; ++k) {
      float g = silu_f(sg[k] + bf2f(dgp[k]) + bf2f(gp[k]));
      ax[k] += g * bf2f(dup[k]);
    }
  }

  u16x8 sup = *(const u16x8*)&su_t[(size_t)r * DD + c];
  float v[8];
  float sum = 0.f;
#pragma unroll
  for (int k = 0; k < 8; ++k) { v[k] = bf2f(sup[k]) + ax[k]; sum += v[k]; }
#pragma unroll
  for (int off = 1; off <= 8; off <<= 1) sum += __shfl_xor(sum, off);
  float mean = sum * (1.0f / 128.0f);
  float sq = 0.f;
#pragma unroll
  for (int k = 0; k < 8; ++k) { v[k] -= mean; sq += v[k] * v[k]; }
#pragma unroll
  for (int off = 1; off <= 8; off <<= 1) sq += __shfl_xor(sq, off);
  float rs = rsqrtf(sq * (1.0f / 128.0f) + 1e-5f);

  float4 gm0 = *(const float4*)&gamma[c];
  float4 gm1 = *(const float4*)&gamma[c + 4];
  float4 bt0 = *(const float4*)&beta[c];
  float4 bt1 = *(const float4*)&beta[c + 4];
  float4 rr0 = *(const float4*)&resid[(size_t)r * DD + c];
  float4 rr1 = *(const float4*)&resid[(size_t)r * DD + c + 4];
  float gmv[8] = {gm0.x, gm0.y, gm0.z, gm0.w, gm1.x, gm1.y, gm1.z, gm1.w};
  float btv[8] = {bt0.x, bt0.y, bt0.z, bt0.w, bt1.x, bt1.y, bt1.z, bt1.w};
  float rrv[8] = {rr0.x, rr0.y, rr0.z, rr0.w, rr1.x, rr1.y, rr1.z, rr1.w};
  float o[8];
#pragma unroll
  for (int k = 0; k < 8; ++k)
    o[k] = silu_f(v[k] * rs * gmv[k] + btv[k]) + rrv[k];
  float4 o0 = {o[0], o[1], o[2], o[3]};
  float4 o1 = {o[4], o[5], o[6], o[7]};
  *(float4*)&out[(size_t)r * DD + c] = o0;
  *(float4*)&out[(size_t)r * DD + c + 4] = o1;
}

extern "C" void kernel_launch(void* const* d_in, const int* in_sizes, int n_in,
                              void* d_out, int out_size, void* d_ws, size_t ws_size,
                              hipStream_t stream) {
  const float* x   = (const float*)d_in[0];
  const float* ex  = (const float*)d_in[1];
  const float* lga = (const float*)d_in[2];
  const int* gei   = (const int*)d_in[3];
  const int* lgei  = (const int*)d_in[4];
  int N   = in_sizes[0] / DD;
  int E   = in_sizes[3] / 2;
  int ELG = in_sizes[4] / 2;

  char* p = (char*)d_ws;
  size_t off = 0;
  auto alloc = [&](size_t bytes) { char* q = p + off; off += (bytes + 255) & ~255ull; return q; };

  u16* wt     = (u16*)alloc((size_t)10 * 16384 * 2);
  float* biasF = (float*)alloc(768 * 4);
  u16* sgE    = (u16*)alloc((size_t)E * DD * 2);        // 128 MB
  u16* dgduE  = (u16*)alloc((size_t)E * 2 * DD * 2);    // 256 MB
  u16* suE    = (u16*)alloc((size_t)E * DD * 2);        // 128 MB
  int  maxME  = (ELG > E) ? ELG : E;
  u16* egpB   = (u16*)alloc((size_t)maxME * DD * 2);    // 128 MB, shared L1/L2
  u16* sgN    = (u16*)alloc((size_t)N * DD * 2);
  u16* dgduN  = (u16*)alloc((size_t)N * 2 * DD * 2);
  u16* suN    = (u16*)alloc((size_t)N * DD * 2);
  int* cnt_e  = (int*)alloc((size_t)E * 4);
  int* rptr_e = (int*)alloc((size_t)(E + 1) * 4);
  int* head_e = (int*)alloc((size_t)E * 4);
  int* srcs_e = (int*)alloc((size_t)ELG * 4);
  int* pos_e  = (int*)alloc((size_t)ELG * 4);
  int* cnt_n  = (int*)alloc((size_t)N * 4);
  int* rptr_n = (int*)alloc((size_t)(N + 1) * 4);
  int* head_n = (int*)alloc((size_t)N * 4);
  int* srcs_n = (int*)alloc((size_t)E * 4);
  int* pos_n  = (int*)alloc((size_t)E * 4);
  int* bsum   = (int*)alloc(512 * 4);
  if (ws_size < off) return;  // visible failure if ws too small

  float* xn_out = (float*)d_out;
  float* ea_out = (float*)d_out + (size_t)N * DD;

  // --- prep: weights + folded biases ---
  // wt slots 0..9 = eu{sg,dg,eg,du,su}, nu{sg,dg,eg,du,su}
  prep_weights<<<10, 256, 0, stream>>>(
      (const float*)d_in[5], (const float*)d_in[7], (const float*)d_in[9],
      (const float*)d_in[13], (const float*)d_in[11],
      (const float*)d_in[17], (const float*)d_in[19], (const float*)d_in[21],
      (const float*)d_in[25], (const float*)d_in[23], wt);
  fold_bias<<<1, 128, 0, stream>>>(
      (const float*)d_in[6], (const float*)d_in[8], (const float*)d_in[10],
      (const float*)d_in[14], (const float*)d_in[12],
      (const float*)d_in[18], (const float*)d_in[20], (const float*)d_in[22],
      (const float*)d_in[26], (const float*)d_in[24], biasF);

  // --- CSR builds: counts -> rowptr -> (src, pos) counting-sort ---
  hipMemsetAsync(cnt_e, 0, (size_t)E * 4, stream);
  hipMemsetAsync(cnt_n, 0, (size_t)N * 4, stream);
  hist_kernel<<<(ELG + 255) / 256, 256, 0, stream>>>(lgei + ELG, ELG, cnt_e);
  hist_kernel<<<(E + 255) / 256, 256, 0, stream>>>(gei + E, E, cnt_n);

  int NBe = (E + 1023) / 1024;
  scan1_kernel<<<NBe, 256, 0, stream>>>(cnt_e, E, rptr_e, bsum);
  scan2_kernel<<<1, 256, 0, stream>>>(bsum, NBe);
  scan3_kernel<<<(E + 255) / 256, 256, 0, stream>>>(rptr_e, bsum, E, ELG, head_e);
  eid_kernel<<<(ELG + 255) / 256, 256, 0, stream>>>(lgei, lgei + ELG, ELG, head_e,
                                                    srcs_e, pos_e);

  int NBn = (N + 1023) / 1024;
  scan1_kernel<<<NBn, 256, 0, stream>>>(cnt_n, N, rptr_n, bsum);
  scan2_kernel<<<1, 256, 0, stream>>>(bsum, NBn);
  scan3_kernel<<<(N + 255) / 256, 256, 0, stream>>>(rptr_n, bsum, N, E, head_n);
  eid_kernel<<<(E + 255) / 256, 256, 0, stream>>>(gei, gei + E, E, head_n,
                                                  srcs_n, pos_n);

  // --- Layer 1 (line graph; rows = g's edges) ---
  proj_kernel<true><<<(E + 127) / 128, 256, 0, stream>>>(
      E, ex, wt, biasF, nullptr, sgE, dgduE, suE);
  proj_kernel<false><<<(ELG + 127) / 128, 256, 0, stream>>>(
      ELG, lga, wt + 2 * 16384, nullptr, pos_e, egpB, nullptr, nullptr);
  gfin_kernel<<<(E + 15) / 16, 256, 0, stream>>>(
      E, rptr_e, srcs_e, sgE, dgduE, suE, egpB,
      (const float*)d_in[15], (const float*)d_in[16], ex, ea_out);

  // --- Layer 2 (bond graph; attr = ea from d_out, f32 stream) ---
  proj_kernel<true><<<(N + 127) / 128, 256, 0, stream>>>(
      N, x, wt + 5 * 16384, biasF + 384, nullptr, sgN, dgduN, suN);
  proj_kernel<false><<<(E + 127) / 128, 256, 0, stream>>>(
      E, ea_out, wt + 7 * 16384, nullptr, pos_n, egpB, nullptr, nullptr);
  gfin_kernel<<<(N + 15) / 16, 256, 0, stream>>>(
      N, rptr_n, srcs_n, sgN, dgduN, suN, egpB,
      (const float*)d_in[27], (const float*)d_in[28], x, xn_out);
}